// Round 1
// baseline (3633.358 us; speedup 1.0000x reference)
//
#include <hip/hip_runtime.h>
#include <hip/hip_bf16.h>
#include <math.h>

#define TT   2048
#define HID  1024
#define NHEAD 8
#define NKVH  2
#define HD   128
#define QKVN 1536   // (8 + 2*2) * 128
#define NEXP 64
#define NTOP 6
#define I_T  512
#define I_V  256
#define I_S  1024

// ---------------- RMSNorm: one block per token row ----------------
__global__ __launch_bounds__(256) void rmsnorm_kernel(const float* __restrict__ x,
                                                      const float* __restrict__ w,
                                                      float* __restrict__ out) {
  const int row = blockIdx.x;
  const int t = threadIdx.x;
  const float4 v = *(const float4*)(x + (size_t)row * HID + t * 4);
  float ss = v.x*v.x + v.y*v.y + v.z*v.z + v.w*v.w;
#pragma unroll
  for (int m = 32; m >= 1; m >>= 1) ss += __shfl_xor(ss, m);
  __shared__ float red[4];
  __shared__ float rrs;
  if ((t & 63) == 0) red[t >> 6] = ss;
  __syncthreads();
  if (t == 0) rrs = rsqrtf((red[0] + red[1] + red[2] + red[3]) * (1.0f / HID) + 1e-5f);
  __syncthreads();
  const float rr = rrs;
  const float4 wv = *(const float4*)(w + t * 4);
  float4 o;
  o.x = v.x * wv.x * rr; o.y = v.y * wv.y * rr;
  o.z = v.z * wv.z * rr; o.w = v.w * wv.w * rr;
  *(float4*)(out + (size_t)row * HID + t * 4) = o;
}

// ---------------- Generic fp32 GEMM: C[M,N] = A[M,K] @ B[K,N] (+resid) ----------------
// block: 16 rows (blockIdx.y) x 256 cols (blockIdx.x), K multiple of 512.
template<bool RES>
__global__ __launch_bounds__(256) void gemm16_kernel(const float* __restrict__ A,
                                                     const float* __restrict__ B,
                                                     const float* __restrict__ resid,
                                                     float* __restrict__ C,
                                                     int N, int K) {
  __shared__ float As[16 * 512];
  const int t = threadIdx.x;
  const int m0 = blockIdx.y * 16;
  const int col = blockIdx.x * 256 + t;
  float acc[16];
#pragma unroll
  for (int m = 0; m < 16; ++m) acc[m] = 0.f;
  for (int kc = 0; kc < K; kc += 512) {
    __syncthreads();
#pragma unroll
    for (int q = 0; q < 8; ++q) {
      int idx = t + 256 * q;
      int r = idx >> 7, c4 = (idx & 127) << 2;
      *(float4*)&As[r * 512 + c4] = *(const float4*)&A[(size_t)(m0 + r) * K + kc + c4];
    }
    __syncthreads();
    for (int h = 0; h < 512; h += 4) {
      float4 xr[16];
#pragma unroll
      for (int m = 0; m < 16; ++m) xr[m] = *(const float4*)&As[m * 512 + h];
#pragma unroll
      for (int jj = 0; jj < 4; ++jj) {
        float b = B[(size_t)(kc + h + jj) * N + col];
#pragma unroll
        for (int m = 0; m < 16; ++m)
          acc[m] += ((const float*)&xr[m])[jj] * b;
      }
    }
  }
#pragma unroll
  for (int m = 0; m < 16; ++m) {
    float v = acc[m];
    if (RES) v += resid[(size_t)(m0 + m) * N + col];
    C[(size_t)(m0 + m) * N + col] = v;
  }
}

// ---------------- mRoPE (in-place on q,k sections of qkv) ----------------
__global__ __launch_bounds__(256) void rope_kernel(float* __restrict__ qkv,
                                                   const int* __restrict__ pos) {
  const int tok = blockIdx.x;
  const int t = threadIdx.x;
  float* row = qkv + (size_t)tok * QKVN;
  for (int p = t; p < 640; p += 256) {   // 512 q-pairs + 128 k-pairs
    int fi, base;
    if (p < 512) { int head = p >> 6; fi = p & 63; base = head * HD; }
    else         { int pp = p - 512; int head = pp >> 6; fi = pp & 63; base = NHEAD * HD + head * HD; }
    int axis = (fi < 22) ? 0 : (fi < 44 ? 1 : 2);
    float posv = (float)pos[axis * TT + tok];      // B=1: (3,1,S)
    float invf = powf(500000.0f, -((float)(2 * fi)) / 128.0f);
    float ang = posv * invf;
    float s, c;
    sincosf(ang, &s, &c);
    float x1 = row[base + 2 * fi], x2 = row[base + 2 * fi + 1];
    row[base + 2 * fi]     = x1 * c - x2 * s;
    row[base + 2 * fi + 1] = x1 * s + x2 * c;
  }
}

// ---------------- Flash attention, fp32. block = (qtile16, head) ----------------
__global__ __launch_bounds__(256) void attn_kernel(const float* __restrict__ qkv,
                                                   float* __restrict__ out) {
  const int qt = blockIdx.x, hh = blockIdx.y;
  const int t = threadIdx.x;
  const int m = t >> 4;       // q-row within tile
  const int j = t & 15;       // d-chunk owner (8 floats)
  const int q0 = qt * 16;
  const int kvh = hh >> 2;    // GQA: repeat(k,4) -> q-head h uses kv-head h/4
  __shared__ float Ks[16][128];
  __shared__ float Vs[16][128];
  float qreg[8];
  {
    const float* qptr = qkv + (size_t)(q0 + m) * QKVN + hh * HD + j * 8;
    *(float4*)&qreg[0] = *(const float4*)qptr;
    *(float4*)&qreg[4] = *(const float4*)(qptr + 4);
  }
  float o[8];
#pragma unroll
  for (int k = 0; k < 8; ++k) o[k] = 0.f;
  float mrow = -INFINITY, lrow = 0.f;
  const float scale = 0.08838834764831845f;   // 1/sqrt(128)
  const int ktmax = q0 >> 4;
  for (int kt = 0; kt <= ktmax; ++kt) {
    const int kv0 = kt * 16;
    __syncthreads();
#pragma unroll
    for (int q = 0; q < 2; ++q) {
      int idx = t + 256 * q;             // 0..511 float4 slots
      int r = idx >> 5, c4 = (idx & 31) * 4;
      const float* kp = qkv + (size_t)(kv0 + r) * QKVN + NHEAD * HD + kvh * HD + c4;
      const float* vp = qkv + (size_t)(kv0 + r) * QKVN + (NHEAD + NKVH) * HD + kvh * HD + c4;
      *(float4*)&Ks[r][c4] = *(const float4*)kp;
      *(float4*)&Vs[r][c4] = *(const float4*)vp;
    }
    __syncthreads();
    float s[16];
#pragma unroll
    for (int jj = 0; jj < 16; ++jj) {
      float4 a = *(const float4*)&Ks[jj][j * 8];
      float4 b = *(const float4*)&Ks[jj][j * 8 + 4];
      s[jj] = qreg[0]*a.x + qreg[1]*a.y + qreg[2]*a.z + qreg[3]*a.w
            + qreg[4]*b.x + qreg[5]*b.y + qreg[6]*b.z + qreg[7]*b.w;
    }
#pragma unroll
    for (int msk = 1; msk <= 8; msk <<= 1) {
#pragma unroll
      for (int jj = 0; jj < 16; ++jj) s[jj] += __shfl_xor(s[jj], msk);
    }
    float smax = -INFINITY;
#pragma unroll
    for (int jj = 0; jj < 16; ++jj) {
      float v = (kv0 + jj <= q0 + m) ? s[jj] * scale : -INFINITY;
      s[jj] = v;
      smax = fmaxf(smax, v);
    }
    const float mnew = fmaxf(mrow, smax);
    const float corr = expf(mrow - mnew);   // exp(-inf)=0 on first tile
    float p[16];
    float psum = 0.f;
#pragma unroll
    for (int jj = 0; jj < 16; ++jj) { p[jj] = expf(s[jj] - mnew); psum += p[jj]; }
    lrow = lrow * corr + psum;
#pragma unroll
    for (int k = 0; k < 8; ++k) o[k] *= corr;
#pragma unroll
    for (int jj = 0; jj < 16; ++jj) {
      float pv = p[jj];
      float4 a = *(const float4*)&Vs[jj][j * 8];
      float4 b = *(const float4*)&Vs[jj][j * 8 + 4];
      o[0] += pv * a.x; o[1] += pv * a.y; o[2] += pv * a.z; o[3] += pv * a.w;
      o[4] += pv * b.x; o[5] += pv * b.y; o[6] += pv * b.z; o[7] += pv * b.w;
    }
    mrow = mnew;
  }
  const float inv = 1.f / lrow;
  float* op = out + (size_t)(q0 + m) * HID + hh * HD + j * 8;
  float4 o0 = make_float4(o[0]*inv, o[1]*inv, o[2]*inv, o[3]*inv);
  float4 o1 = make_float4(o[4]*inv, o[5]*inv, o[6]*inv, o[7]*inv);
  *(float4*)op = o0;
  *(float4*)(op + 4) = o1;
}

// ---------------- Gating: sigmoid, top-6 of (score+bias), normalized weights ----------------
__global__ __launch_bounds__(256) void gate_kernel(const float* __restrict__ x2,
                                                   const int* __restrict__ vmask,
                                                   const float* __restrict__ tg,
                                                   const float* __restrict__ vg,
                                                   const float* __restrict__ cbias,
                                                   int* __restrict__ counts,
                                                   int* __restrict__ ptok,
                                                   float* __restrict__ pw) {
  const int tok = blockIdx.x;
  const int t = threadIdx.x;
  __shared__ float xs[HID];
  __shared__ float sc[NEXP];
  __shared__ float sb[NEXP];
  *(float4*)&xs[t * 4] = *(const float4*)(x2 + (size_t)tok * HID + t * 4);
  __syncthreads();
  const int vis = (vmask[tok] != 0) ? 1 : 0;
  const float* gw = vis ? vg : tg;
  if (t < NEXP) {
    float acc = 0.f;
    for (int h = 0; h < HID; ++h) acc += xs[h] * gw[h * NEXP + t];
    float s = 1.f / (1.f + expf(-acc));
    sc[t] = s;
    sb[t] = s + cbias[vis * NEXP + t];
  }
  __syncthreads();
  if (t == 0) {
    int chosen[NTOP];
    unsigned long long usedm = 0ULL;
    float wsum = 0.f;
    for (int k = 0; k < NTOP; ++k) {
      float best = -1e30f; int bi = 0;
      for (int e = 0; e < NEXP; ++e) {
        if ((usedm >> e) & 1ULL) continue;
        if (sb[e] > best) { best = sb[e]; bi = e; }
      }
      usedm |= (1ULL << bi);
      chosen[k] = bi;
      wsum += sc[bi];
    }
    const float inv = 1.f / wsum;
    for (int k = 0; k < NTOP; ++k) {
      int e = chosen[k];
      int slot = vis * NEXP + e;
      int pos = atomicAdd(&counts[slot], 1);
      ptok[slot * TT + pos] = tok;
      pw[slot * TT + pos] = sc[e] * inv;
    }
  }
}

// ---------------- Shared MLP gate+up: ACT = silu(X@WG) * (X@WU) ----------------
__global__ __launch_bounds__(256) void gateup_kernel(const float* __restrict__ X,
                                                     const float* __restrict__ WG,
                                                     const float* __restrict__ WU,
                                                     float* __restrict__ ACT,
                                                     int N, int K) {
  __shared__ float As[16 * 512];
  const int t = threadIdx.x;
  const int m0 = blockIdx.y * 16;
  const int col = blockIdx.x * 256 + t;
  float ag[16], au[16];
#pragma unroll
  for (int m = 0; m < 16; ++m) { ag[m] = 0.f; au[m] = 0.f; }
  for (int kc = 0; kc < K; kc += 512) {
    __syncthreads();
#pragma unroll
    for (int q = 0; q < 8; ++q) {
      int idx = t + 256 * q;
      int r = idx >> 7, c4 = (idx & 127) << 2;
      *(float4*)&As[r * 512 + c4] = *(const float4*)&X[(size_t)(m0 + r) * K + kc + c4];
    }
    __syncthreads();
    for (int h = 0; h < 512; h += 4) {
      float4 xr[16];
#pragma unroll
      for (int m = 0; m < 16; ++m) xr[m] = *(const float4*)&As[m * 512 + h];
#pragma unroll
      for (int jj = 0; jj < 4; ++jj) {
        float wg = WG[(size_t)(kc + h + jj) * N + col];
        float wu = WU[(size_t)(kc + h + jj) * N + col];
#pragma unroll
        for (int m = 0; m < 16; ++m) {
          float xv = ((const float*)&xr[m])[jj];
          ag[m] += xv * wg;
          au[m] += xv * wu;
        }
      }
    }
  }
#pragma unroll
  for (int m = 0; m < 16; ++m) {
    float g = ag[m];
    float a = g / (1.f + expf(-g)) * au[m];
    ACT[(size_t)(m0 + m) * N + col] = a;
  }
}

// ---------------- Grouped expert FFN (gather x rows, FFN, scatter-add) ----------------
template<int I>
__global__ __launch_bounds__(256) void moe_ffn_kernel(const float* __restrict__ X,
                                                      const float* __restrict__ WG,
                                                      const float* __restrict__ WU,
                                                      const float* __restrict__ WD,
                                                      const int* __restrict__ counts,
                                                      const int* __restrict__ ptok,
                                                      const float* __restrict__ pw,
                                                      float* __restrict__ OUT,
                                                      int slotBase) {
  const int e = blockIdx.y;
  const int slot = slotBase + e;
  const int cnt = counts[slot];
  const int r0 = blockIdx.x * 16;
  if (r0 >= cnt) return;
  const int nr = min(16, cnt - r0);
  const int t = threadIdx.x;
  __shared__ float As[16 * 512];    // x chunks, then act tile (16*I <= 16*512)
  __shared__ int toks[16];
  __shared__ float tws[16];
  if (t < 16) {
    toks[t] = (t < nr) ? ptok[slot * TT + r0 + t] : 0;
    tws[t]  = (t < nr) ? pw[slot * TT + r0 + t] : 0.f;
  }
  __syncthreads();
  constexpr int NC = I / 256;
  float ag[NC][16], au[NC][16];
#pragma unroll
  for (int c = 0; c < NC; ++c)
#pragma unroll
    for (int m = 0; m < 16; ++m) { ag[c][m] = 0.f; au[c][m] = 0.f; }
  const float* wgb = WG + (size_t)e * HID * I;
  const float* wub = WU + (size_t)e * HID * I;
  for (int kc = 0; kc < HID; kc += 512) {
    __syncthreads();
#pragma unroll
    for (int q = 0; q < 8; ++q) {
      int idx = t + 256 * q;
      int r = idx >> 7, c4 = (idx & 127) << 2;
      float4 v = make_float4(0.f, 0.f, 0.f, 0.f);
      if (r < nr) v = *(const float4*)&X[(size_t)toks[r] * HID + kc + c4];
      *(float4*)&As[r * 512 + c4] = v;
    }
    __syncthreads();
    for (int h = 0; h < 512; h += 4) {
      float4 xr[16];
#pragma unroll
      for (int m = 0; m < 16; ++m) xr[m] = *(const float4*)&As[m * 512 + h];
#pragma unroll
      for (int jj = 0; jj < 4; ++jj) {
#pragma unroll
        for (int c = 0; c < NC; ++c) {
          float wg = wgb[(size_t)(kc + h + jj) * I + t + 256 * c];
          float wu = wub[(size_t)(kc + h + jj) * I + t + 256 * c];
#pragma unroll
          for (int m = 0; m < 16; ++m) {
            float xv = ((const float*)&xr[m])[jj];
            ag[c][m] += xv * wg;
            au[c][m] += xv * wu;
          }
        }
      }
    }
  }
  __syncthreads();
#pragma unroll
  for (int c = 0; c < NC; ++c) {
    int colI = t + 256 * c;
#pragma unroll
    for (int m = 0; m < 16; ++m) {
      float g = ag[c][m];
      As[m * I + colI] = g / (1.f + expf(-g)) * au[c][m];
    }
  }
  __syncthreads();
  float o[4][16];
#pragma unroll
  for (int c = 0; c < 4; ++c)
#pragma unroll
    for (int m = 0; m < 16; ++m) o[c][m] = 0.f;
  const float* wdb = WD + (size_t)e * I * HID;
  for (int i = 0; i < I; i += 4) {
    float4 ar[16];
#pragma unroll
    for (int m = 0; m < 16; ++m) ar[m] = *(const float4*)&As[m * I + i];
#pragma unroll
    for (int jj = 0; jj < 4; ++jj) {
#pragma unroll
      for (int c = 0; c < 4; ++c) {
        float wd = wdb[(size_t)(i + jj) * HID + t + 256 * c];
#pragma unroll
        for (int m = 0; m < 16; ++m) {
          float av = ((const float*)&ar[m])[jj];
          o[c][m] += av * wd;
        }
      }
    }
  }
#pragma unroll
  for (int c = 0; c < 4; ++c) {
    for (int m = 0; m < nr; ++m) {
      atomicAdd(&OUT[(size_t)toks[m] * HID + t + 256 * c], o[c][m] * tws[m]);
    }
  }
}

// ---------------- out = a + b ----------------
__global__ __launch_bounds__(256) void add2_kernel(const float* __restrict__ a,
                                                   const float* __restrict__ b,
                                                   float* __restrict__ out) {
  const size_t i = ((size_t)blockIdx.x * 256 + threadIdx.x) * 4;
  const float4 va = *(const float4*)(a + i);
  const float4 vb = *(const float4*)(b + i);
  float4 o;
  o.x = va.x + vb.x; o.y = va.y + vb.y; o.z = va.z + vb.z; o.w = va.w + vb.w;
  *(float4*)(out + i) = o;
}

extern "C" void kernel_launch(void* const* d_in, const int* in_sizes, int n_in,
                              void* d_out, int out_size, void* d_ws, size_t ws_size,
                              hipStream_t stream) {
  const float* hidden   = (const float*)d_in[0];
  const int*   positions= (const int*)d_in[1];
  const int*   vmask    = (const int*)d_in[2];
  const float* w_qkv    = (const float*)d_in[3];
  const float* w_o      = (const float*)d_in[4];
  const float* ln1      = (const float*)d_in[5];
  const float* ln2      = (const float*)d_in[6];
  const float* tgw      = (const float*)d_in[7];
  const float* vgw      = (const float*)d_in[8];
  const float* cbias    = (const float*)d_in[9];
  const float* twg      = (const float*)d_in[10];
  const float* twu      = (const float*)d_in[11];
  const float* twd      = (const float*)d_in[12];
  const float* vwg      = (const float*)d_in[13];
  const float* vwu      = (const float*)d_in[14];
  const float* vwd      = (const float*)d_in[15];
  const float* swg      = (const float*)d_in[16];
  const float* swu      = (const float*)d_in[17];
  const float* swd      = (const float*)d_in[18];
  float* out = (float*)d_out;

  char* ws = (char*)d_ws;
  size_t off = 0;
  auto alloc = [&](size_t bytes) -> void* {
    void* p = ws + off;
    off += (bytes + 255) & ~(size_t)255;
    return p;
  };
  float* xn    = (float*)alloc((size_t)TT * HID * 4);
  float* qkv   = (float*)alloc((size_t)TT * QKVN * 4);
  float* attn  = (float*)alloc((size_t)TT * HID * 4);
  float* hbuf  = (float*)alloc((size_t)TT * HID * 4);
  float* x2    = (float*)alloc((size_t)TT * HID * 4);
  float* moe   = (float*)alloc((size_t)TT * HID * 4);
  float* acts  = (float*)alloc((size_t)TT * I_S * 4);
  int*   counts= (int*)alloc(128 * 4);
  int*   ptok  = (int*)alloc((size_t)128 * TT * 4);
  float* pwgt  = (float*)alloc((size_t)128 * TT * 4);

  rmsnorm_kernel<<<TT, 256, 0, stream>>>(hidden, ln1, xn);
  gemm16_kernel<false><<<dim3(QKVN / 256, TT / 16), 256, 0, stream>>>(xn, w_qkv, nullptr, qkv, QKVN, HID);
  rope_kernel<<<TT, 256, 0, stream>>>(qkv, positions);
  attn_kernel<<<dim3(TT / 16, NHEAD), 256, 0, stream>>>(qkv, attn);
  gemm16_kernel<true><<<dim3(HID / 256, TT / 16), 256, 0, stream>>>(attn, w_o, hidden, hbuf, HID, HID);
  rmsnorm_kernel<<<TT, 256, 0, stream>>>(hbuf, ln2, x2);
  hipMemsetAsync(counts, 0, 128 * 4, stream);
  gate_kernel<<<TT, 256, 0, stream>>>(x2, vmask, tgw, vgw, cbias, counts, ptok, pwgt);
  gateup_kernel<<<dim3(I_S / 256, TT / 16), 256, 0, stream>>>(x2, swg, swu, acts, I_S, HID);
  gemm16_kernel<false><<<dim3(HID / 256, TT / 16), 256, 0, stream>>>(acts, swd, nullptr, moe, HID, I_S);
  moe_ffn_kernel<I_T><<<dim3(TT / 16, NEXP), 256, 0, stream>>>(x2, twg, twu, twd, counts, ptok, pwgt, moe, 0);
  moe_ffn_kernel<I_V><<<dim3(TT / 16, NEXP), 256, 0, stream>>>(x2, vwg, vwu, vwd, counts, ptok, pwgt, moe, NEXP);
  add2_kernel<<<(TT * HID) / 1024, 256, 0, stream>>>(hbuf, moe, out);
}

// Round 3
// 1938.189 us; speedup vs baseline: 1.8746x; 1.8746x over previous
//
#include <hip/hip_runtime.h>
#include <hip/hip_bf16.h>
#include <math.h>

#define TT   2048
#define HID  1024
#define NHEAD 8
#define NKVH  2
#define HD   128
#define QKVN 1536
#define NEXP 64
#define NTOP 6
#define I_T  512
#define I_V  256
#define I_S  1024
#define SBASE ((size_t)12288 * 512)   // ACT elem offset of shared region

typedef unsigned short u16;
typedef __attribute__((ext_vector_type(8))) short short8v;
typedef __attribute__((ext_vector_type(4))) float f32x4;

__device__ inline u16 f2bf(float f) {
  __hip_bfloat16 h = __float2bfloat16(f);
  return *reinterpret_cast<u16*>(&h);
}

__device__ inline f32x4 mfma16(short8v a, short8v b, f32x4 c) {
  return __builtin_amdgcn_mfma_f32_16x16x32_bf16(a, b, c, 0, 0, 0);
}

// ---- stage weight slab: W fp32 [kd rows, ldw stride], cols [c0,c0+nc) -> LDS bf16
// LDS layout (k-packed-8): elem(k,c) at ((k>>3)*nc + c)*8 + (k&7)
__device__ inline void stage_w(const float* __restrict__ W, int ldw, int c0, int nc,
                               int kd, u16* lds) {
  const int t = threadIdx.x;
  const int tpr = nc >> 2;          // threads per row (4 cols each)
  const int rpi = 256 / tpr;        // rows per iteration
  const int c4 = (t % tpr) << 2;
  const int r0 = t / tpr;
  for (int k = r0; k < kd; k += rpi) {
    float4 v = *(const float4*)&W[(size_t)k * ldw + c0 + c4];
    u16* dst = lds + ((size_t)(k >> 3) * nc) * 8 + (k & 7);
    dst[(c4 + 0) * 8] = f2bf(v.x);
    dst[(c4 + 1) * 8] = f2bf(v.y);
    dst[(c4 + 2) * 8] = f2bf(v.z);
    dst[(c4 + 3) * 8] = f2bf(v.w);
  }
}

// ---- stage A tile: 32 rows x 128 k (bf16), XOR-swizzled rows; rowsrc<0 -> zeros
__device__ inline void stage_a(const u16* __restrict__ X, const long long* rowsrc,
                               int kc, u16* ldsA) {
  const int t = threadIdx.x;
#pragma unroll
  for (int it = 0; it < 2; ++it) {
    int chunk = t + (it << 8);
    int row = chunk >> 4;
    int k16 = chunk & 15;
    long long rs = rowsrc[row];
    uint4 v = make_uint4(0u, 0u, 0u, 0u);
    if (rs >= 0) v = *(const uint4*)(X + rs + kc + (k16 << 3));
    char* dst = (char*)ldsA + row * 256 + (((k16 << 4)) ^ ((row & 7) << 4));
    *(uint4*)dst = v;
  }
}

__device__ inline short8v read_a(const u16* ldsA, int rowBase, int kb, int lane) {
  int row = rowBase + (lane & 15);
  int koff = kb + ((lane >> 4) << 3);
  const char* p = (const char*)ldsA + row * 256 + ((koff * 2) ^ ((row & 7) << 4));
  return *(const short8v*)p;
}

__device__ inline short8v read_w(const u16* slab, int nc, int col0, int kglob, int lane) {
  int c = col0 + (lane & 15);
  int k = kglob + ((lane >> 4) << 3);
  return *(const short8v*)(slab + ((size_t)(k >> 3) * nc + c) * 8);
}

// ---------------- RMSNorm (templated outputs) ----------------
template<bool F32, bool BF>
__global__ __launch_bounds__(256) void rmsnorm_kernel(const float* __restrict__ x,
                                                      const float* __restrict__ w,
                                                      float* __restrict__ o32,
                                                      u16* __restrict__ obf) {
  const int row = blockIdx.x;
  const int t = threadIdx.x;
  const float4 v = *(const float4*)(x + (size_t)row * HID + t * 4);
  float ss = v.x*v.x + v.y*v.y + v.z*v.z + v.w*v.w;
#pragma unroll
  for (int m = 32; m >= 1; m >>= 1) ss += __shfl_xor(ss, m);
  __shared__ float red[4];
  __shared__ float rrs;
  if ((t & 63) == 0) red[t >> 6] = ss;
  __syncthreads();
  if (t == 0) rrs = rsqrtf((red[0] + red[1] + red[2] + red[3]) * (1.0f / HID) + 1e-5f);
  __syncthreads();
  const float rr = rrs;
  const float4 wv = *(const float4*)(w + t * 4);
  float4 o;
  o.x = v.x * wv.x * rr; o.y = v.y * wv.y * rr;
  o.z = v.z * wv.z * rr; o.w = v.w * wv.w * rr;
  if (F32) *(float4*)(o32 + (size_t)row * HID + t * 4) = o;
  if (BF) {
    u16 u[4] = { f2bf(o.x), f2bf(o.y), f2bf(o.z), f2bf(o.w) };
    *(uint2*)(obf + (size_t)row * HID + t * 4) = *(uint2*)u;
  }
}

// ---------------- fp32 GEMM (round-1, known-good): C[M,N]=A[M,K]@B[K,N] (+resid) ----
template<bool RES>
__global__ __launch_bounds__(256) void gemm16_kernel(const float* __restrict__ A,
                                                     const float* __restrict__ B,
                                                     const float* __restrict__ resid,
                                                     float* __restrict__ C,
                                                     int N, int K) {
  __shared__ float As[16 * 512];
  const int t = threadIdx.x;
  const int m0 = blockIdx.y * 16;
  const int col = blockIdx.x * 256 + t;
  float acc[16];
#pragma unroll
  for (int m = 0; m < 16; ++m) acc[m] = 0.f;
  for (int kc = 0; kc < K; kc += 512) {
    __syncthreads();
#pragma unroll
    for (int q = 0; q < 8; ++q) {
      int idx = t + 256 * q;
      int r = idx >> 7, c4 = (idx & 127) << 2;
      *(float4*)&As[r * 512 + c4] = *(const float4*)&A[(size_t)(m0 + r) * K + kc + c4];
    }
    __syncthreads();
    for (int h = 0; h < 512; h += 4) {
      float4 xr[16];
#pragma unroll
      for (int m = 0; m < 16; ++m) xr[m] = *(const float4*)&As[m * 512 + h];
#pragma unroll
      for (int jj = 0; jj < 4; ++jj) {
        float b = B[(size_t)(kc + h + jj) * N + col];
#pragma unroll
        for (int m = 0; m < 16; ++m)
          acc[m] += ((const float*)&xr[m])[jj] * b;
      }
    }
  }
#pragma unroll
  for (int m = 0; m < 16; ++m) {
    float v = acc[m];
    if (RES) v += resid[(size_t)(m0 + m) * N + col];
    C[(size_t)(m0 + m) * N + col] = v;
  }
}

// ---------------- mRoPE (in-place on q,k of qkv, fp32) ----------------
__global__ __launch_bounds__(256) void rope_kernel(float* __restrict__ qkv,
                                                   const int* __restrict__ pos) {
  const int tok = blockIdx.x;
  const int t = threadIdx.x;
  float* row = qkv + (size_t)tok * QKVN;
  for (int p = t; p < 640; p += 256) {
    int fi, base;
    if (p < 512) { int head = p >> 6; fi = p & 63; base = head * HD; }
    else         { int pp = p - 512; int head = pp >> 6; fi = pp & 63; base = NHEAD * HD + head * HD; }
    int axis = (fi < 22) ? 0 : (fi < 44 ? 1 : 2);
    float posv = (float)pos[axis * TT + tok];
    float invf = powf(500000.0f, -((float)(2 * fi)) / 128.0f);
    float ang = posv * invf;
    float s, c;
    sincosf(ang, &s, &c);
    float x1 = row[base + 2 * fi], x2 = row[base + 2 * fi + 1];
    row[base + 2 * fi]     = x1 * c - x2 * s;
    row[base + 2 * fi + 1] = x1 * s + x2 * c;
  }
}

// ---------------- Flash attention fp32 (round-1, known-good), fp32 out ----------------
__global__ __launch_bounds__(256) void attn_kernel(const float* __restrict__ qkv,
                                                   float* __restrict__ out) {
  const int qt = blockIdx.x, hh = blockIdx.y;
  const int t = threadIdx.x;
  const int m = t >> 4;
  const int j = t & 15;
  const int q0 = qt * 16;
  const int kvh = hh >> 2;
  __shared__ float Ks[16][128];
  __shared__ float Vs[16][128];
  float qreg[8];
  {
    const float* qptr = qkv + (size_t)(q0 + m) * QKVN + hh * HD + j * 8;
    *(float4*)&qreg[0] = *(const float4*)qptr;
    *(float4*)&qreg[4] = *(const float4*)(qptr + 4);
  }
  float o[8];
#pragma unroll
  for (int k = 0; k < 8; ++k) o[k] = 0.f;
  float mrow = -INFINITY, lrow = 0.f;
  const float scale = 0.08838834764831845f;
  const int ktmax = q0 >> 4;
  for (int kt = 0; kt <= ktmax; ++kt) {
    const int kv0 = kt * 16;
    __syncthreads();
#pragma unroll
    for (int q = 0; q < 2; ++q) {
      int idx = t + 256 * q;
      int r = idx >> 5, c4 = (idx & 31) * 4;
      const float* kp = qkv + (size_t)(kv0 + r) * QKVN + NHEAD * HD + kvh * HD + c4;
      const float* vp = qkv + (size_t)(kv0 + r) * QKVN + (NHEAD + NKVH) * HD + kvh * HD + c4;
      *(float4*)&Ks[r][c4] = *(const float4*)kp;
      *(float4*)&Vs[r][c4] = *(const float4*)vp;
    }
    __syncthreads();
    float s[16];
#pragma unroll
    for (int jj = 0; jj < 16; ++jj) {
      float4 a = *(const float4*)&Ks[jj][j * 8];
      float4 b = *(const float4*)&Ks[jj][j * 8 + 4];
      s[jj] = qreg[0]*a.x + qreg[1]*a.y + qreg[2]*a.z + qreg[3]*a.w
            + qreg[4]*b.x + qreg[5]*b.y + qreg[6]*b.z + qreg[7]*b.w;
    }
#pragma unroll
    for (int msk = 1; msk <= 8; msk <<= 1) {
#pragma unroll
      for (int jj = 0; jj < 16; ++jj) s[jj] += __shfl_xor(s[jj], msk);
    }
    float smax = -INFINITY;
#pragma unroll
    for (int jj = 0; jj < 16; ++jj) {
      float v = (kv0 + jj <= q0 + m) ? s[jj] * scale : -INFINITY;
      s[jj] = v;
      smax = fmaxf(smax, v);
    }
    const float mnew = fmaxf(mrow, smax);
    const float corr = expf(mrow - mnew);
    float p[16];
    float psum = 0.f;
#pragma unroll
    for (int jj = 0; jj < 16; ++jj) { p[jj] = expf(s[jj] - mnew); psum += p[jj]; }
    lrow = lrow * corr + psum;
#pragma unroll
    for (int k = 0; k < 8; ++k) o[k] *= corr;
#pragma unroll
    for (int jj = 0; jj < 16; ++jj) {
      float pv = p[jj];
      float4 a = *(const float4*)&Vs[jj][j * 8];
      float4 b = *(const float4*)&Vs[jj][j * 8 + 4];
      o[0] += pv * a.x; o[1] += pv * a.y; o[2] += pv * a.z; o[3] += pv * a.w;
      o[4] += pv * b.x; o[5] += pv * b.y; o[6] += pv * b.z; o[7] += pv * b.w;
    }
    mrow = mnew;
  }
  const float inv = 1.f / lrow;
  float* op = out + (size_t)(q0 + m) * HID + hh * HD + j * 8;
  float4 o0 = make_float4(o[0]*inv, o[1]*inv, o[2]*inv, o[3]*inv);
  float4 o1 = make_float4(o[4]*inv, o[5]*inv, o[6]*inv, o[7]*inv);
  *(float4*)op = o0;
  *(float4*)(op + 4) = o1;
}

// ---------------- Gating (fp32, known-good) ----------------
__global__ __launch_bounds__(256) void gate_kernel(const float* __restrict__ x2,
                                                   const int* __restrict__ vmask,
                                                   const float* __restrict__ tg,
                                                   const float* __restrict__ vg,
                                                   const float* __restrict__ cbias,
                                                   int* __restrict__ counts,
                                                   int* __restrict__ ptok,
                                                   float* __restrict__ pw) {
  const int tok = blockIdx.x;
  const int t = threadIdx.x;
  __shared__ float xs[HID];
  __shared__ float sc[NEXP];
  __shared__ float sb[NEXP];
  *(float4*)&xs[t * 4] = *(const float4*)(x2 + (size_t)tok * HID + t * 4);
  __syncthreads();
  const int vis = (vmask[tok] != 0) ? 1 : 0;
  const float* gw = vis ? vg : tg;
  if (t < NEXP) {
    float acc = 0.f;
    for (int h = 0; h < HID; ++h) acc += xs[h] * gw[h * NEXP + t];
    float s = 1.f / (1.f + expf(-acc));
    sc[t] = s;
    sb[t] = s + cbias[vis * NEXP + t];
  }
  __syncthreads();
  if (t == 0) {
    int chosen[NTOP];
    unsigned long long usedm = 0ULL;
    float wsum = 0.f;
    for (int k = 0; k < NTOP; ++k) {
      float best = -1e30f; int bi = 0;
      for (int e = 0; e < NEXP; ++e) {
        if ((usedm >> e) & 1ULL) continue;
        if (sb[e] > best) { best = sb[e]; bi = e; }
      }
      usedm |= (1ULL << bi);
      chosen[k] = bi;
      wsum += sc[bi];
    }
    const float inv = 1.f / wsum;
    for (int k = 0; k < NTOP; ++k) {
      int e = chosen[k];
      int slot = vis * NEXP + e;
      int pos = atomicAdd(&counts[slot], 1);
      ptok[slot * TT + pos] = tok;
      pw[slot * TT + pos] = sc[e] * inv;
    }
  }
}

__global__ void scan_kernel(const int* __restrict__ counts, int* __restrict__ rowoff) {
  if (threadIdx.x == 0 && blockIdx.x == 0) {
    int s = 0;
    for (int i = 0; i < 128; ++i) { rowoff[i] = s; s += counts[i]; }
    rowoff[128] = s;
  }
}

// ---- per-slot ACT element base / stride
template<int MODE>
__device__ inline void act_base(const int* rowoff, int slot, size_t& eb, int& stride) {
  if (MODE == 0) { eb = (size_t)rowoff[slot] * 512; stride = 512; }
  else if (MODE == 1) {
    int Rt = rowoff[64];
    eb = (size_t)Rt * 512 + (size_t)(rowoff[slot] - Rt) * 256; stride = 256;
  } else { eb = SBASE; stride = 1024; }
}

// ---------------- gate+up slab kernel -> ACT bf16 ----------------
template<int IDIM, int MODE>
__global__ __launch_bounds__(256) void gateup_mfma(const u16* __restrict__ X,
                                                   const float* __restrict__ WG,
                                                   const float* __restrict__ WU,
                                                   const int* __restrict__ counts,
                                                   const int* __restrict__ ptok,
                                                   const float* __restrict__ pw,
                                                   const int* __restrict__ rowoff,
                                                   u16* __restrict__ ACT) {
  constexpr int CH = IDIM / 32;
  __shared__ u16 slabG[(HID / 8) * 32 * 8];
  __shared__ u16 slabU[(HID / 8) * 32 * 8];
  __shared__ u16 ldsA[32 * 128];
  __shared__ float uTmp[32 * 33];
  __shared__ long long rowsrc[32];
  __shared__ float tws[32];

  int id = blockIdx.x + gridDim.x * blockIdx.y;
  if (MODE != 2) {
    int nb = gridDim.x * gridDim.y;
    int q = nb >> 3;
    id = (id & 7) * q + (id >> 3);
  }
  const int e = id / CH;
  const int c0 = (id % CH) * 32;

  int cnt, mstart, mend, slot = 0;
  size_t eb; int stride;
  if (MODE == 2) {
    cnt = TT;
    int rows = TT / gridDim.y;
    mstart = e * rows; mend = mstart + rows;
    eb = SBASE; stride = 1024;
  } else {
    slot = (MODE == 1 ? NEXP : 0) + e;
    cnt = counts[slot];
    mstart = 0; mend = cnt;
    act_base<MODE>(rowoff, slot, eb, stride);
  }
  const size_t wb = (MODE == 2) ? 0 : (size_t)e * HID * IDIM;
  stage_w(WG + wb, IDIM, c0, 32, HID, slabG);
  stage_w(WU + wb, IDIM, c0, 32, HID, slabU);

  const int w = threadIdx.x >> 6, lane = threadIdx.x & 63;
  const int rowHalf = (w & 1) << 4;
  const u16* slab = (w >> 1) ? slabU : slabG;

  for (int m0 = mstart; m0 < mend; m0 += 32) {
    __syncthreads();
    if (threadIdx.x < 32) {
      int gi = m0 + threadIdx.x;
      long long rs = -1; float wv = 0.f;
      if (gi < cnt) {
        int tok = (MODE == 2) ? gi : ptok[slot * TT + gi];
        rs = (long long)tok * HID;
        wv = (MODE == 2) ? 1.f : pw[slot * TT + gi];
      }
      rowsrc[threadIdx.x] = rs; tws[threadIdx.x] = wv;
    }
    f32x4 acc0 = {0.f,0.f,0.f,0.f}, acc1 = {0.f,0.f,0.f,0.f};
    for (int kc = 0; kc < HID; kc += 128) {
      __syncthreads();
      stage_a(X, rowsrc, kc, ldsA);
      __syncthreads();
#pragma unroll
      for (int ks = 0; ks < 4; ++ks) {
        short8v a  = read_a(ldsA, rowHalf, ks * 32, lane);
        short8v b0 = read_w(slab, 32, 0,  kc + ks * 32, lane);
        short8v b1 = read_w(slab, 32, 16, kc + ks * 32, lane);
        acc0 = mfma16(a, b0, acc0);
        acc1 = mfma16(a, b1, acc1);
      }
    }
    __syncthreads();
    if (w >> 1) {   // up waves stash to LDS
#pragma unroll
      for (int i = 0; i < 4; ++i) {
        int r = rowHalf + ((lane >> 4) << 2) + i;
        uTmp[r * 33 + (lane & 15)] = acc0[i];
        uTmp[r * 33 + 16 + (lane & 15)] = acc1[i];
      }
    }
    __syncthreads();
    if (!(w >> 1)) {  // gate waves: silu(g)*u*pw -> ACT
#pragma unroll
      for (int nfr = 0; nfr < 2; ++nfr) {
        f32x4 acc = nfr ? acc1 : acc0;
#pragma unroll
        for (int i = 0; i < 4; ++i) {
          int r = rowHalf + ((lane >> 4) << 2) + i;
          int gi = m0 + r;
          if (gi < cnt) {
            float g = acc[i];
            float u = uTmp[r * 33 + nfr * 16 + (lane & 15)];
            float a = g / (1.f + expf(-g)) * u * tws[r];
            ACT[eb + (size_t)gi * stride + c0 + nfr * 16 + (lane & 15)] = f2bf(a);
          }
        }
      }
    }
  }
}

// ---------------- down-proj slab kernel: atomicAdd into OUT ----------------
template<int IDIM, int MODE>
__global__ __launch_bounds__(256) void down_mfma(const u16* __restrict__ ACT,
                                                 const float* __restrict__ WD,
                                                 const int* __restrict__ counts,
                                                 const int* __restrict__ ptok,
                                                 const int* __restrict__ rowoff,
                                                 float* __restrict__ OUT) {
  constexpr int CH = HID / 64;   // 16
  __shared__ u16 slab[(IDIM / 8) * 64 * 8];
  __shared__ u16 ldsA[32 * 128];
  __shared__ long long rowsrc[32];
  __shared__ int toks[32];

  int id = blockIdx.x + gridDim.x * blockIdx.y;
  if (MODE != 2) {
    int nb = gridDim.x * gridDim.y;
    int q = nb >> 3;
    id = (id & 7) * q + (id >> 3);
  }
  const int e = id / CH;
  const int c0 = (id % CH) * 64;

  int cnt, mstart, mend, slot = 0;
  size_t eb; int stride;
  if (MODE == 2) {
    cnt = TT;
    int rows = TT / gridDim.y;
    mstart = e * rows; mend = mstart + rows;
    eb = SBASE; stride = 1024;
  } else {
    slot = (MODE == 1 ? NEXP : 0) + e;
    cnt = counts[slot];
    mstart = 0; mend = cnt;
    act_base<MODE>(rowoff, slot, eb, stride);
  }
  const float* wd = WD + ((MODE == 2) ? 0 : (size_t)e * IDIM * HID);
  stage_w(wd, HID, c0, 64, IDIM, slab);

  const int w = threadIdx.x >> 6, lane = threadIdx.x & 63;
  const int rowHalf = (w & 1) << 4, colHalf = (w >> 1) << 5;

  for (int m0 = mstart; m0 < mend; m0 += 32) {
    __syncthreads();
    if (threadIdx.x < 32) {
      int gi = m0 + threadIdx.x;
      long long rs = -1; int tk = 0;
      if (gi < cnt) {
        rs = (long long)(eb + (size_t)gi * stride);
        tk = (MODE == 2) ? gi : ptok[slot * TT + gi];
      }
      rowsrc[threadIdx.x] = rs; toks[threadIdx.x] = tk;
    }
    f32x4 acc0 = {0.f,0.f,0.f,0.f}, acc1 = {0.f,0.f,0.f,0.f};
    for (int kc = 0; kc < IDIM; kc += 128) {
      __syncthreads();
      stage_a(ACT, rowsrc, kc, ldsA);
      __syncthreads();
#pragma unroll
      for (int ks = 0; ks < 4; ++ks) {
        short8v a  = read_a(ldsA, rowHalf, ks * 32, lane);
        short8v b0 = read_w(slab, 64, colHalf,      kc + ks * 32, lane);
        short8v b1 = read_w(slab, 64, colHalf + 16, kc + ks * 32, lane);
        acc0 = mfma16(a, b0, acc0);
        acc1 = mfma16(a, b1, acc1);
      }
    }
    __syncthreads();
#pragma unroll
    for (int nfr = 0; nfr < 2; ++nfr) {
      f32x4 acc = nfr ? acc1 : acc0;
#pragma unroll
      for (int i = 0; i < 4; ++i) {
        int r = rowHalf + ((lane >> 4) << 2) + i;
        int gi = m0 + r;
        if (gi < cnt) {
          atomicAdd(&OUT[(size_t)toks[r] * HID + c0 + colHalf + nfr * 16 + (lane & 15)],
                    acc[i]);
        }
      }
    }
  }
}

// ---------------- out = a + b ----------------
__global__ __launch_bounds__(256) void add2_kernel(const float* __restrict__ a,
                                                   const float* __restrict__ b,
                                                   float* __restrict__ out) {
  const size_t i = ((size_t)blockIdx.x * 256 + threadIdx.x) * 4;
  const float4 va = *(const float4*)(a + i);
  const float4 vb = *(const float4*)(b + i);
  float4 o;
  o.x = va.x + vb.x; o.y = va.y + vb.y; o.z = va.z + vb.z; o.w = va.w + vb.w;
  *(float4*)(out + i) = o;
}

extern "C" void kernel_launch(void* const* d_in, const int* in_sizes, int n_in,
                              void* d_out, int out_size, void* d_ws, size_t ws_size,
                              hipStream_t stream) {
  const float* hidden   = (const float*)d_in[0];
  const int*   positions= (const int*)d_in[1];
  const int*   vmask    = (const int*)d_in[2];
  const float* w_qkv    = (const float*)d_in[3];
  const float* w_o      = (const float*)d_in[4];
  const float* ln1      = (const float*)d_in[5];
  const float* ln2      = (const float*)d_in[6];
  const float* tgw      = (const float*)d_in[7];
  const float* vgw      = (const float*)d_in[8];
  const float* cbias    = (const float*)d_in[9];
  const float* twg      = (const float*)d_in[10];
  const float* twu      = (const float*)d_in[11];
  const float* twd      = (const float*)d_in[12];
  const float* vwg      = (const float*)d_in[13];
  const float* vwu      = (const float*)d_in[14];
  const float* vwd      = (const float*)d_in[15];
  const float* swg      = (const float*)d_in[16];
  const float* swu      = (const float*)d_in[17];
  const float* swd      = (const float*)d_in[18];
  float* out = (float*)d_out;

  char* ws = (char*)d_ws;
  size_t off = 0;
  auto alloc = [&](size_t bytes) -> void* {
    void* p = ws + off;
    off += (bytes + 255) & ~(size_t)255;
    return p;
  };
  float* xn    = (float*)alloc((size_t)TT * HID * 4);   // rmsnorm1 out; later attn out
  float* qkv   = (float*)alloc((size_t)TT * QKVN * 4);  // qkv; later x2 (fp32) aliases
  float* hbuf  = (float*)alloc((size_t)TT * HID * 4);
  u16*   xb2   = (u16*)alloc((size_t)TT * HID * 2);
  float* moe   = (float*)alloc((size_t)TT * HID * 4);
  u16*   ACT   = (u16*)alloc((SBASE + (size_t)TT * 1024) * 2);
  int*   counts= (int*)alloc(128 * 4);
  int*   rowoff= (int*)alloc(129 * 4);
  int*   ptok  = (int*)alloc((size_t)128 * TT * 4);
  float* pwgt  = (float*)alloc((size_t)128 * TT * 4);
  float* x2    = qkv;          // qkv dead after attn_kernel; reuse for x2
  float* attnO = xn;           // xn dead after QKV GEMM; reuse for attention out

  hipMemsetAsync(counts, 0, 128 * 4, stream);
  hipMemsetAsync(moe, 0, (size_t)TT * HID * 4, stream);

  // --- precise (fp32) pre-gate path: round-1 known-good kernels ---
  rmsnorm_kernel<true, false><<<TT, 256, 0, stream>>>(hidden, ln1, xn, nullptr);
  gemm16_kernel<false><<<dim3(QKVN / 256, TT / 16), 256, 0, stream>>>(xn, w_qkv, nullptr, qkv, QKVN, HID);
  rope_kernel<<<TT, 256, 0, stream>>>(qkv, positions);
  attn_kernel<<<dim3(TT / 16, NHEAD), 256, 0, stream>>>(qkv, attnO);
  gemm16_kernel<true><<<dim3(HID / 256, TT / 16), 256, 0, stream>>>(attnO, w_o, hidden, hbuf, HID, HID);
  rmsnorm_kernel<true, true><<<TT, 256, 0, stream>>>(hbuf, ln2, x2, xb2);
  gate_kernel<<<TT, 256, 0, stream>>>(x2, vmask, tgw, vgw, cbias, counts, ptok, pwgt);
  scan_kernel<<<1, 64, 0, stream>>>(counts, rowoff);

  // --- bf16 slab-MFMA MoE + shared MLP (round-2 machinery) ---
  gateup_mfma<I_S, 2><<<dim3(I_S / 32, 8), 256, 0, stream>>>(xb2, swg, swu, nullptr, nullptr, nullptr, rowoff, ACT);
  gateup_mfma<I_T, 0><<<dim3(I_T / 32, NEXP), 256, 0, stream>>>(xb2, twg, twu, counts, ptok, pwgt, rowoff, ACT);
  gateup_mfma<I_V, 1><<<dim3(I_V / 32, NEXP), 256, 0, stream>>>(xb2, vwg, vwu, counts, ptok, pwgt, rowoff, ACT);

  down_mfma<I_S, 2><<<dim3(HID / 64, 8), 256, 0, stream>>>(ACT, swd, nullptr, nullptr, rowoff, moe);
  down_mfma<I_T, 0><<<dim3(HID / 64, NEXP), 256, 0, stream>>>(ACT, twd, counts, ptok, rowoff, moe);
  down_mfma<I_V, 1><<<dim3(HID / 64, NEXP), 256, 0, stream>>>(ACT, vwd, counts, ptok, rowoff, moe);

  add2_kernel<<<(TT * HID) / 1024, 256, 0, stream>>>(hbuf, moe, out);
}

// Round 4
// 1395.480 us; speedup vs baseline: 2.6037x; 1.3889x over previous
//
#include <hip/hip_runtime.h>
#include <hip/hip_bf16.h>
#include <math.h>

#define TT   2048
#define HID  1024
#define NHEAD 8
#define NKVH  2
#define HD   128
#define QKVN 1536
#define NEXP 64
#define NTOP 6
#define I_T  512
#define I_V  256
#define I_S  1024
#define SBASE ((size_t)12288 * 512)   // ACT elem offset of shared region

typedef unsigned short u16;
typedef __attribute__((ext_vector_type(8))) short short8v;
typedef __attribute__((ext_vector_type(4))) float f32x4;

__device__ inline u16 f2bf(float f) {
  __hip_bfloat16 h = __float2bfloat16(f);
  return *reinterpret_cast<u16*>(&h);
}
__device__ inline float bfu2f(u16 u) {
  unsigned x = ((unsigned)u) << 16;
  return __uint_as_float(x);
}
__device__ inline void split2(float f, u16& h, u16& l) {
  h = f2bf(f);
  l = f2bf(f - bfu2f(h));
}
__device__ inline void split8(const float* f, u16* h, u16* l) {
#pragma unroll
  for (int i = 0; i < 8; ++i) split2(f[i], h[i], l[i]);
}

__device__ inline f32x4 mfma16(short8v a, short8v b, f32x4 c) {
  return __builtin_amdgcn_mfma_f32_16x16x32_bf16(a, b, c, 0, 0, 0);
}

// ================= MoE machinery (round-3, passing, unchanged) =================

// stage weight slab: W fp32 [kd rows, ldw stride], cols [c0,c0+nc) -> LDS bf16
// LDS layout (k-packed-8): elem(k,c) at ((k>>3)*nc + c)*8 + (k&7)
__device__ inline void stage_w(const float* __restrict__ W, int ldw, int c0, int nc,
                               int kd, u16* lds) {
  const int t = threadIdx.x;
  const int tpr = nc >> 2;
  const int rpi = 256 / tpr;
  const int c4 = (t % tpr) << 2;
  const int r0 = t / tpr;
  for (int k = r0; k < kd; k += rpi) {
    float4 v = *(const float4*)&W[(size_t)k * ldw + c0 + c4];
    u16* dst = lds + ((size_t)(k >> 3) * nc) * 8 + (k & 7);
    dst[(c4 + 0) * 8] = f2bf(v.x);
    dst[(c4 + 1) * 8] = f2bf(v.y);
    dst[(c4 + 2) * 8] = f2bf(v.z);
    dst[(c4 + 3) * 8] = f2bf(v.w);
  }
}

// stage A tile: 32 rows x 128 k (bf16), XOR-swizzled rows; rowsrc<0 -> zeros
__device__ inline void stage_a(const u16* __restrict__ X, const long long* rowsrc,
                               int kc, u16* ldsA) {
  const int t = threadIdx.x;
#pragma unroll
  for (int it = 0; it < 2; ++it) {
    int chunk = t + (it << 8);
    int row = chunk >> 4;
    int k16 = chunk & 15;
    long long rs = rowsrc[row];
    uint4 v = make_uint4(0u, 0u, 0u, 0u);
    if (rs >= 0) v = *(const uint4*)(X + rs + kc + (k16 << 3));
    char* dst = (char*)ldsA + row * 256 + (((k16 << 4)) ^ ((row & 7) << 4));
    *(uint4*)dst = v;
  }
}

__device__ inline short8v read_a(const u16* ldsA, int rowBase, int kb, int lane) {
  int row = rowBase + (lane & 15);
  int koff = kb + ((lane >> 4) << 3);
  const char* p = (const char*)ldsA + row * 256 + ((koff * 2) ^ ((row & 7) << 4));
  return *(const short8v*)p;
}

__device__ inline short8v read_w(const u16* slab, int nc, int col0, int kglob, int lane) {
  int c = col0 + (lane & 15);
  int k = kglob + ((lane >> 4) << 3);
  return *(const short8v*)(slab + ((size_t)(k >> 3) * nc + c) * 8);
}

// ---------------- RMSNorm (templated outputs: fp32, bf16-hi, bf16-lo) ----------------
template<bool F32, bool BF, bool LO>
__global__ __launch_bounds__(256) void rmsnorm_kernel(const float* __restrict__ x,
                                                      const float* __restrict__ w,
                                                      float* __restrict__ o32,
                                                      u16* __restrict__ obfH,
                                                      u16* __restrict__ obfL) {
  const int row = blockIdx.x;
  const int t = threadIdx.x;
  const float4 v = *(const float4*)(x + (size_t)row * HID + t * 4);
  float ss = v.x*v.x + v.y*v.y + v.z*v.z + v.w*v.w;
#pragma unroll
  for (int m = 32; m >= 1; m >>= 1) ss += __shfl_xor(ss, m);
  __shared__ float red[4];
  __shared__ float rrs;
  if ((t & 63) == 0) red[t >> 6] = ss;
  __syncthreads();
  if (t == 0) rrs = rsqrtf((red[0] + red[1] + red[2] + red[3]) * (1.0f / HID) + 1e-5f);
  __syncthreads();
  const float rr = rrs;
  const float4 wv = *(const float4*)(w + t * 4);
  float o[4];
  o[0] = v.x * wv.x * rr; o[1] = v.y * wv.y * rr;
  o[2] = v.z * wv.z * rr; o[3] = v.w * wv.w * rr;
  if (F32) *(float4*)(o32 + (size_t)row * HID + t * 4) = *(float4*)o;
  if (BF) {
    u16 h[4], l[4];
#pragma unroll
    for (int i = 0; i < 4; ++i) split2(o[i], h[i], l[i]);
    *(uint2*)(obfH + (size_t)row * HID + t * 4) = *(uint2*)h;
    if (LO) *(uint2*)(obfL + (size_t)row * HID + t * 4) = *(uint2*)l;
  }
}

// ---------------- pack W fp32 [K=1024][N] -> hi/lo bf16, k-packed-8 slabs of 32 cols ---
// gidx(k,c) = ((c>>5)*128 + (k>>3))*256 + (c&31)*8 + (k&7)
__global__ __launch_bounds__(256) void convert_w(const float* __restrict__ W, int N,
                                                 u16* __restrict__ PH,
                                                 u16* __restrict__ PL) {
  const int c = blockIdx.x * 256 + threadIdx.x;
  const int k8 = blockIdx.y;
  float f[8];
#pragma unroll
  for (int e = 0; e < 8; ++e) f[e] = W[(size_t)(k8 * 8 + e) * N + c];
  u16 h8[8], l8[8];
  split8(f, h8, l8);
  size_t gi = ((size_t)(c >> 5) * 128 + k8) * 256 + (size_t)(c & 31) * 8;
  *(uint4*)&PH[gi] = *(uint4*)h8;
  *(uint4*)&PL[gi] = *(uint4*)l8;
}

// ---------------- dense split-bf16 GEMM: C[2048,N] = A @ W (+resid), exact-ish -------
// A given as row-major bf16 hi/lo [2048][1024]; W pre-packed hi/lo slabs.
template<bool RES>
__global__ __launch_bounds__(256) void dense_split(const u16* __restrict__ AH,
                                                   const u16* __restrict__ AL,
                                                   const u16* __restrict__ WPH,
                                                   const u16* __restrict__ WPL,
                                                   const float* __restrict__ resid,
                                                   float* __restrict__ C, int N) {
  __shared__ u16 sWH[32768], sWL[32768];   // 1024 k x 32 cols
  __shared__ u16 sAH[4096],  sAL[4096];    // 32 rows x 128 k
  const int t = threadIdx.x;
  const int cs = blockIdx.x;
  const int c0 = cs * 32;
  const int rows = TT / gridDim.y;
  const int mstart = blockIdx.y * rows, mend = mstart + rows;
  {
    const u16* gh = WPH + (size_t)cs * 32768;
    const u16* gl = WPL + (size_t)cs * 32768;
#pragma unroll
    for (int r = 0; r < 16; ++r) {
      int i8 = (t + 256 * r) * 8;
      *(uint4*)&sWH[i8] = *(const uint4*)&gh[i8];
      *(uint4*)&sWL[i8] = *(const uint4*)&gl[i8];
    }
  }
  const int w = t >> 6, lane = t & 63;
  const int rowHalf = (w & 1) << 4, colHalf = (w >> 1) << 4;
  for (int m0 = mstart; m0 < mend; m0 += 32) {
    f32x4 hh = {0.f,0.f,0.f,0.f}, hl = {0.f,0.f,0.f,0.f};
    f32x4 lh = {0.f,0.f,0.f,0.f}, ll = {0.f,0.f,0.f,0.f};
    for (int kc = 0; kc < HID; kc += 128) {
      __syncthreads();
#pragma unroll
      for (int r = 0; r < 2; ++r) {
        int task = t + 256 * r;        // 512: row = task>>4, kg = task&15
        int row = task >> 4, kg = task & 15;
        size_t g = (size_t)(m0 + row) * HID + kc + kg * 8;
        *(uint4*)&sAH[(kg * 32 + row) * 8] = *(const uint4*)&AH[g];
        *(uint4*)&sAL[(kg * 32 + row) * 8] = *(const uint4*)&AL[g];
      }
      __syncthreads();
#pragma unroll
      for (int ks = 0; ks < 4; ++ks) {
        int arow = rowHalf + (lane & 15);
        int akg = ks * 4 + (lane >> 4);
        short8v ah = *(const short8v*)&sAH[(akg * 32 + arow) * 8];
        short8v al = *(const short8v*)&sAL[(akg * 32 + arow) * 8];
        int wcol = colHalf + (lane & 15);
        int wkg = (kc >> 3) + ks * 4 + (lane >> 4);
        short8v bh = *(const short8v*)&sWH[(wkg * 32 + wcol) * 8];
        short8v bl = *(const short8v*)&sWL[(wkg * 32 + wcol) * 8];
        hh = mfma16(ah, bh, hh);
        hl = mfma16(ah, bl, hl);
        lh = mfma16(al, bh, lh);
        ll = mfma16(al, bl, ll);
      }
    }
    f32x4 acc = (hh + hl) + (lh + ll);
#pragma unroll
    for (int i = 0; i < 4; ++i) {
      int r = m0 + rowHalf + ((lane >> 4) << 2) + i;
      int c = c0 + colHalf + (lane & 15);
      float v = acc[i];
      if (RES) v += resid[(size_t)r * N + c];
      C[(size_t)r * N + c] = v;
    }
  }
}

// ---------------- mRoPE (in-place on q,k of qkv, fp32) ----------------
__global__ __launch_bounds__(256) void rope_kernel(float* __restrict__ qkv,
                                                   const int* __restrict__ pos) {
  const int tok = blockIdx.x;
  const int t = threadIdx.x;
  float* row = qkv + (size_t)tok * QKVN;
  for (int p = t; p < 640; p += 256) {
    int fi, base;
    if (p < 512) { int head = p >> 6; fi = p & 63; base = head * HD; }
    else         { int pp = p - 512; int head = pp >> 6; fi = pp & 63; base = NHEAD * HD + head * HD; }
    int axis = (fi < 22) ? 0 : (fi < 44 ? 1 : 2);
    float posv = (float)pos[axis * TT + tok];
    float invf = powf(500000.0f, -((float)(2 * fi)) / 128.0f);
    float ang = posv * invf;
    float s, c;
    sincosf(ang, &s, &c);
    float x1 = row[base + 2 * fi], x2 = row[base + 2 * fi + 1];
    row[base + 2 * fi]     = x1 * c - x2 * s;
    row[base + 2 * fi + 1] = x1 * s + x2 * c;
  }
}

// ---------------- split-bf16 MFMA flash attention ----------------
// Block: 128 thr (2 waves), 32 q-rows, 1 head. Per 32-key tile: K/V hi/lo in LDS,
// MFMA QK^T (4 cross terms), fp32 online softmax, P hi/lo via LDS, MFMA PV (3 terms).
__global__ __launch_bounds__(128) void attn_mfma(const float* __restrict__ qkv,
                                                 u16* __restrict__ aoH,
                                                 u16* __restrict__ aoL) {
  const int qb = blockIdx.x;
  const int head = blockIdx.y;
  const int t = threadIdx.x;
  const int w = t >> 6, lane = t & 63;
  const int qw0 = qb * 32 + w * 16;
  const int kvh = head >> 2;
  const int kbase = NHEAD * HD + kvh * HD;
  const int vbase = (NHEAD + NKVH) * HD + kvh * HD;

  __shared__ u16 Kh[4096], Kl[4096];   // elem(d,key): ((d>>3)*32+key)*8 + (d&7)
  __shared__ u16 Vh[4096], Vl[4096];   // elem(k,c):   ((k>>3)*128+c)*8 + (k&7)
  __shared__ u16 Ph[2][512], Pl[2][512];

  // Q fragments (hi/lo), 4 d-chunks of 32
  short8v qh[4], ql[4];
  {
    const int m = lane & 15, g = lane >> 4;
    const float* qp = qkv + (size_t)(qw0 + m) * QKVN + head * HD + g * 8;
#pragma unroll
    for (int dc = 0; dc < 4; ++dc) {
      float4 v0 = *(const float4*)(qp + dc * 32);
      float4 v1 = *(const float4*)(qp + dc * 32 + 4);
      float f[8] = {v0.x, v0.y, v0.z, v0.w, v1.x, v1.y, v1.z, v1.w};
      u16 h8[8], l8[8];
      split8(f, h8, l8);
      qh[dc] = *(short8v*)h8;
      ql[dc] = *(short8v*)l8;
    }
  }

  f32x4 o[8];
#pragma unroll
  for (int dt = 0; dt < 8; ++dt) o[dt] = (f32x4){0.f,0.f,0.f,0.f};
  float mr[4] = {-INFINITY, -INFINITY, -INFINITY, -INFINITY};
  float lr[4] = {0.f, 0.f, 0.f, 0.f};
  const float scale = 0.08838834764831845f;

  const int nkt = qb + 1;
  for (int kt = 0; kt < nkt; ++kt) {
    const int kv0 = kt * 32;
    // ---- stage K (hi/lo): tasks (d8 0..15, key 0..31)
#pragma unroll
    for (int r = 0; r < 4; ++r) {
      int task = t + 128 * r;
      int key = task & 31, d8 = task >> 5;
      const float* kp = qkv + (size_t)(kv0 + key) * QKVN + kbase + d8 * 8;
      float4 a = *(const float4*)kp, b = *(const float4*)(kp + 4);
      float f[8] = {a.x, a.y, a.z, a.w, b.x, b.y, b.z, b.w};
      u16 h8[8], l8[8];
      split8(f, h8, l8);
      int base = (d8 * 32 + key) * 8;
      *(uint4*)&Kh[base] = *(uint4*)h8;
      *(uint4*)&Kl[base] = *(uint4*)l8;
    }
    // ---- stage V (hi/lo): tasks (k8 0..3, c 0..127)
#pragma unroll
    for (int r = 0; r < 4; ++r) {
      int task = t + 128 * r;
      int c = task & 127, k8 = task >> 7;
      float f[8];
#pragma unroll
      for (int e = 0; e < 8; ++e)
        f[e] = qkv[(size_t)(kv0 + k8 * 8 + e) * QKVN + vbase + c];
      u16 h8[8], l8[8];
      split8(f, h8, l8);
      int base = (k8 * 128 + c) * 8;
      *(uint4*)&Vh[base] = *(uint4*)h8;
      *(uint4*)&Vl[base] = *(uint4*)l8;
    }
    __syncthreads();
    if (kv0 <= qw0 + 15) {
      // ---- QK^T
      f32x4 s[2];
#pragma unroll
      for (int nt = 0; nt < 2; ++nt) {
        f32x4 shh = {0.f,0.f,0.f,0.f}, shl = {0.f,0.f,0.f,0.f};
        f32x4 slh = {0.f,0.f,0.f,0.f}, sll = {0.f,0.f,0.f,0.f};
#pragma unroll
        for (int dc = 0; dc < 4; ++dc) {
          int kb_ = ((dc * 4 + (lane >> 4)) * 32 + nt * 16 + (lane & 15)) * 8;
          short8v bh = *(const short8v*)&Kh[kb_];
          short8v bl = *(const short8v*)&Kl[kb_];
          shh = mfma16(qh[dc], bh, shh);
          shl = mfma16(qh[dc], bl, shl);
          slh = mfma16(ql[dc], bh, slh);
          sll = mfma16(ql[dc], bl, sll);
        }
        s[nt] = (shh + shl) + (slh + sll);
      }
      // ---- scale + causal mask + row max
      float rmax[4];
#pragma unroll
      for (int i = 0; i < 4; ++i) {
        int qrow = qw0 + ((lane >> 4) << 2) + i;
#pragma unroll
        for (int nt = 0; nt < 2; ++nt) {
          int key = kv0 + nt * 16 + (lane & 15);
          float v = s[nt][i] * scale;
          s[nt][i] = (key <= qrow) ? v : -INFINITY;
        }
        rmax[i] = fmaxf(s[0][i], s[1][i]);
      }
#pragma unroll
      for (int msk = 1; msk <= 8; msk <<= 1)
#pragma unroll
        for (int i = 0; i < 4; ++i) rmax[i] = fmaxf(rmax[i], __shfl_xor(rmax[i], msk));
      // ---- online softmax update
      float corr[4];
#pragma unroll
      for (int i = 0; i < 4; ++i) {
        float mn = fmaxf(mr[i], rmax[i]);
        corr[i] = expf(mr[i] - mn);
        mr[i] = mn;
      }
      float p[2][4], ps[4];
#pragma unroll
      for (int nt = 0; nt < 2; ++nt)
#pragma unroll
        for (int i = 0; i < 4; ++i) p[nt][i] = expf(s[nt][i] - mr[i]);
#pragma unroll
      for (int i = 0; i < 4; ++i) ps[i] = p[0][i] + p[1][i];
#pragma unroll
      for (int msk = 1; msk <= 8; msk <<= 1)
#pragma unroll
        for (int i = 0; i < 4; ++i) ps[i] += __shfl_xor(ps[i], msk);
#pragma unroll
      for (int i = 0; i < 4; ++i) lr[i] = lr[i] * corr[i] + ps[i];
#pragma unroll
      for (int dt = 0; dt < 8; ++dt)
#pragma unroll
        for (int i = 0; i < 4; ++i) o[dt][i] *= corr[i];
      // ---- P -> LDS (hi/lo), wave-private
      u16* phw = Ph[w];
      u16* plw = Pl[w];
#pragma unroll
      for (int nt = 0; nt < 2; ++nt)
#pragma unroll
        for (int i = 0; i < 4; ++i) {
          int q = ((lane >> 4) << 2) + i;
          int kk = nt * 16 + (lane & 15);
          int idx = ((kk >> 3) * 16 + q) * 8 + (kk & 7);
          u16 h, l;
          split2(p[nt][i], h, l);
          phw[idx] = h;
          plw[idx] = l;
        }
      asm volatile("s_waitcnt lgkmcnt(0)" ::: "memory");
      __builtin_amdgcn_sched_barrier(0);
      // ---- PV
      {
        int pbase = ((lane >> 4) * 16 + (lane & 15)) * 8;
        short8v pah = *(const short8v*)&phw[pbase];
        short8v pal = *(const short8v*)&plw[pbase];
#pragma unroll
        for (int dt = 0; dt < 8; ++dt) {
          int vb_ = ((lane >> 4) * 128 + dt * 16 + (lane & 15)) * 8;
          short8v vh = *(const short8v*)&Vh[vb_];
          short8v vl = *(const short8v*)&Vl[vb_];
          o[dt] = mfma16(pah, vh, o[dt]);
          o[dt] = mfma16(pah, vl, o[dt]);
          o[dt] = mfma16(pal, vh, o[dt]);
        }
      }
    }
    __syncthreads();
  }
  // ---- epilogue: normalize, split, store
  float inv[4];
#pragma unroll
  for (int i = 0; i < 4; ++i) inv[i] = 1.f / lr[i];
#pragma unroll
  for (int dt = 0; dt < 8; ++dt)
#pragma unroll
    for (int i = 0; i < 4; ++i) {
      int qrow = qw0 + ((lane >> 4) << 2) + i;
      int col = head * HD + dt * 16 + (lane & 15);
      u16 h, l;
      split2(o[dt][i] * inv[i], h, l);
      aoH[(size_t)qrow * HID + col] = h;
      aoL[(size_t)qrow * HID + col] = l;
    }
}

// ---------------- Gating (fp32, known-good) ----------------
__global__ __launch_bounds__(256) void gate_kernel(const float* __restrict__ x2,
                                                   const int* __restrict__ vmask,
                                                   const float* __restrict__ tg,
                                                   const float* __restrict__ vg,
                                                   const float* __restrict__ cbias,
                                                   int* __restrict__ counts,
                                                   int* __restrict__ ptok,
                                                   float* __restrict__ pw) {
  const int tok = blockIdx.x;
  const int t = threadIdx.x;
  __shared__ float xs[HID];
  __shared__ float sc[NEXP];
  __shared__ float sb[NEXP];
  *(float4*)&xs[t * 4] = *(const float4*)(x2 + (size_t)tok * HID + t * 4);
  __syncthreads();
  const int vis = (vmask[tok] != 0) ? 1 : 0;
  const float* gw = vis ? vg : tg;
  if (t < NEXP) {
    float acc = 0.f;
    for (int h = 0; h < HID; ++h) acc += xs[h] * gw[h * NEXP + t];
    float s = 1.f / (1.f + expf(-acc));
    sc[t] = s;
    sb[t] = s + cbias[vis * NEXP + t];
  }
  __syncthreads();
  if (t == 0) {
    int chosen[NTOP];
    unsigned long long usedm = 0ULL;
    float wsum = 0.f;
    for (int k = 0; k < NTOP; ++k) {
      float best = -1e30f; int bi = 0;
      for (int e = 0; e < NEXP; ++e) {
        if ((usedm >> e) & 1ULL) continue;
        if (sb[e] > best) { best = sb[e]; bi = e; }
      }
      usedm |= (1ULL << bi);
      chosen[k] = bi;
      wsum += sc[bi];
    }
    const float inv = 1.f / wsum;
    for (int k = 0; k < NTOP; ++k) {
      int e = chosen[k];
      int slot = vis * NEXP + e;
      int pos = atomicAdd(&counts[slot], 1);
      ptok[slot * TT + pos] = tok;
      pw[slot * TT + pos] = sc[e] * inv;
    }
  }
}

__global__ void scan_kernel(const int* __restrict__ counts, int* __restrict__ rowoff) {
  if (threadIdx.x == 0 && blockIdx.x == 0) {
    int s = 0;
    for (int i = 0; i < 128; ++i) { rowoff[i] = s; s += counts[i]; }
    rowoff[128] = s;
  }
}

template<int MODE>
__device__ inline void act_base(const int* rowoff, int slot, size_t& eb, int& stride) {
  if (MODE == 0) { eb = (size_t)rowoff[slot] * 512; stride = 512; }
  else if (MODE == 1) {
    int Rt = rowoff[64];
    eb = (size_t)Rt * 512 + (size_t)(rowoff[slot] - Rt) * 256; stride = 256;
  } else { eb = SBASE; stride = 1024; }
}

// ---------------- gate+up slab kernel -> ACT bf16 ----------------
template<int IDIM, int MODE>
__global__ __launch_bounds__(256) void gateup_mfma(const u16* __restrict__ X,
                                                   const float* __restrict__ WG,
                                                   const float* __restrict__ WU,
                                                   const int* __restrict__ counts,
                                                   const int* __restrict__ ptok,
                                                   const float* __restrict__ pw,
                                                   const int* __restrict__ rowoff,
                                                   u16* __restrict__ ACT) {
  constexpr int CH = IDIM / 32;
  __shared__ u16 slabG[(HID / 8) * 32 * 8];
  __shared__ u16 slabU[(HID / 8) * 32 * 8];
  __shared__ u16 ldsA[32 * 128];
  __shared__ float uTmp[32 * 33];
  __shared__ long long rowsrc[32];
  __shared__ float tws[32];

  int id = blockIdx.x + gridDim.x * blockIdx.y;
  if (MODE != 2) {
    int nb = gridDim.x * gridDim.y;
    int q = nb >> 3;
    id = (id & 7) * q + (id >> 3);
  }
  const int e = id / CH;
  const int c0 = (id % CH) * 32;

  int cnt, mstart, mend, slot = 0;
  size_t eb; int stride;
  if (MODE == 2) {
    cnt = TT;
    int rows = TT / gridDim.y;
    mstart = e * rows; mend = mstart + rows;
    eb = SBASE; stride = 1024;
  } else {
    slot = (MODE == 1 ? NEXP : 0) + e;
    cnt = counts[slot];
    mstart = 0; mend = cnt;
    act_base<MODE>(rowoff, slot, eb, stride);
  }
  const size_t wb = (MODE == 2) ? 0 : (size_t)e * HID * IDIM;
  stage_w(WG + wb, IDIM, c0, 32, HID, slabG);
  stage_w(WU + wb, IDIM, c0, 32, HID, slabU);

  const int w = threadIdx.x >> 6, lane = threadIdx.x & 63;
  const int rowHalf = (w & 1) << 4;
  const u16* slab = (w >> 1) ? slabU : slabG;

  for (int m0 = mstart; m0 < mend; m0 += 32) {
    __syncthreads();
    if (threadIdx.x < 32) {
      int gi = m0 + threadIdx.x;
      long long rs = -1; float wv = 0.f;
      if (gi < cnt) {
        int tok = (MODE == 2) ? gi : ptok[slot * TT + gi];
        rs = (long long)tok * HID;
        wv = (MODE == 2) ? 1.f : pw[slot * TT + gi];
      }
      rowsrc[threadIdx.x] = rs; tws[threadIdx.x] = wv;
    }
    f32x4 acc0 = {0.f,0.f,0.f,0.f}, acc1 = {0.f,0.f,0.f,0.f};
    for (int kc = 0; kc < HID; kc += 128) {
      __syncthreads();
      stage_a(X, rowsrc, kc, ldsA);
      __syncthreads();
#pragma unroll
      for (int ks = 0; ks < 4; ++ks) {
        short8v a  = read_a(ldsA, rowHalf, ks * 32, lane);
        short8v b0 = read_w(slab, 32, 0,  kc + ks * 32, lane);
        short8v b1 = read_w(slab, 32, 16, kc + ks * 32, lane);
        acc0 = mfma16(a, b0, acc0);
        acc1 = mfma16(a, b1, acc1);
      }
    }
    __syncthreads();
    if (w >> 1) {
#pragma unroll
      for (int i = 0; i < 4; ++i) {
        int r = rowHalf + ((lane >> 4) << 2) + i;
        uTmp[r * 33 + (lane & 15)] = acc0[i];
        uTmp[r * 33 + 16 + (lane & 15)] = acc1[i];
      }
    }
    __syncthreads();
    if (!(w >> 1)) {
#pragma unroll
      for (int nfr = 0; nfr < 2; ++nfr) {
        f32x4 acc = nfr ? acc1 : acc0;
#pragma unroll
        for (int i = 0; i < 4; ++i) {
          int r = rowHalf + ((lane >> 4) << 2) + i;
          int gi = m0 + r;
          if (gi < cnt) {
            float g = acc[i];
            float u = uTmp[r * 33 + nfr * 16 + (lane & 15)];
            float a = g / (1.f + expf(-g)) * u * tws[r];
            ACT[eb + (size_t)gi * stride + c0 + nfr * 16 + (lane & 15)] = f2bf(a);
          }
        }
      }
    }
  }
}

// ---------------- down-proj slab kernel: atomicAdd into OUT ----------------
template<int IDIM, int MODE>
__global__ __launch_bounds__(256) void down_mfma(const u16* __restrict__ ACT,
                                                 const float* __restrict__ WD,
                                                 const int* __restrict__ counts,
                                                 const int* __restrict__ ptok,
                                                 const int* __restrict__ rowoff,
                                                 float* __restrict__ OUT) {
  constexpr int CH = HID / 64;
  __shared__ u16 slab[(IDIM / 8) * 64 * 8];
  __shared__ u16 ldsA[32 * 128];
  __shared__ long long rowsrc[32];
  __shared__ int toks[32];

  int id = blockIdx.x + gridDim.x * blockIdx.y;
  if (MODE != 2) {
    int nb = gridDim.x * gridDim.y;
    int q = nb >> 3;
    id = (id & 7) * q + (id >> 3);
  }
  const int e = id / CH;
  const int c0 = (id % CH) * 64;

  int cnt, mstart, mend, slot = 0;
  size_t eb; int stride;
  if (MODE == 2) {
    cnt = TT;
    int rows = TT / gridDim.y;
    mstart = e * rows; mend = mstart + rows;
    eb = SBASE; stride = 1024;
  } else {
    slot = (MODE == 1 ? NEXP : 0) + e;
    cnt = counts[slot];
    mstart = 0; mend = cnt;
    act_base<MODE>(rowoff, slot, eb, stride);
  }
  const float* wd = WD + ((MODE == 2) ? 0 : (size_t)e * IDIM * HID);
  stage_w(wd, HID, c0, 64, IDIM, slab);

  const int w = threadIdx.x >> 6, lane = threadIdx.x & 63;
  const int rowHalf = (w & 1) << 4, colHalf = (w >> 1) << 5;

  for (int m0 = mstart; m0 < mend; m0 += 32) {
    __syncthreads();
    if (threadIdx.x < 32) {
      int gi = m0 + threadIdx.x;
      long long rs = -1; int tk = 0;
      if (gi < cnt) {
        rs = (long long)(eb + (size_t)gi * stride);
        tk = (MODE == 2) ? gi : ptok[slot * TT + gi];
      }
      rowsrc[threadIdx.x] = rs; toks[threadIdx.x] = tk;
    }
    f32x4 acc0 = {0.f,0.f,0.f,0.f}, acc1 = {0.f,0.f,0.f,0.f};
    for (int kc = 0; kc < IDIM; kc += 128) {
      __syncthreads();
      stage_a(ACT, rowsrc, kc, ldsA);
      __syncthreads();
#pragma unroll
      for (int ks = 0; ks < 4; ++ks) {
        short8v a  = read_a(ldsA, rowHalf, ks * 32, lane);
        short8v b0 = read_w(slab, 64, colHalf,      kc + ks * 32, lane);
        short8v b1 = read_w(slab, 64, colHalf + 16, kc + ks * 32, lane);
        acc0 = mfma16(a, b0, acc0);
        acc1 = mfma16(a, b1, acc1);
      }
    }
    __syncthreads();
#pragma unroll
    for (int nfr = 0; nfr < 2; ++nfr) {
      f32x4 acc = nfr ? acc1 : acc0;
#pragma unroll
      for (int i = 0; i < 4; ++i) {
        int r = rowHalf + ((lane >> 4) << 2) + i;
        int gi = m0 + r;
        if (gi < cnt) {
          atomicAdd(&OUT[(size_t)toks[r] * HID + c0 + colHalf + nfr * 16 + (lane & 15)],
                    acc[i]);
        }
      }
    }
  }
}

// ---------------- out = a + b ----------------
__global__ __launch_bounds__(256) void add2_kernel(const float* __restrict__ a,
                                                   const float* __restrict__ b,
                                                   float* __restrict__ out) {
  const size_t i = ((size_t)blockIdx.x * 256 + threadIdx.x) * 4;
  const float4 va = *(const float4*)(a + i);
  const float4 vb = *(const float4*)(b + i);
  float4 o;
  o.x = va.x + vb.x; o.y = va.y + vb.y; o.z = va.z + vb.z; o.w = va.w + vb.w;
  *(float4*)(out + i) = o;
}

extern "C" void kernel_launch(void* const* d_in, const int* in_sizes, int n_in,
                              void* d_out, int out_size, void* d_ws, size_t ws_size,
                              hipStream_t stream) {
  const float* hidden   = (const float*)d_in[0];
  const int*   positions= (const int*)d_in[1];
  const int*   vmask    = (const int*)d_in[2];
  const float* w_qkv    = (const float*)d_in[3];
  const float* w_o      = (const float*)d_in[4];
  const float* ln1      = (const float*)d_in[5];
  const float* ln2      = (const float*)d_in[6];
  const float* tgw      = (const float*)d_in[7];
  const float* vgw      = (const float*)d_in[8];
  const float* cbias    = (const float*)d_in[9];
  const float* twg      = (const float*)d_in[10];
  const float* twu      = (const float*)d_in[11];
  const float* twd      = (const float*)d_in[12];
  const float* vwg      = (const float*)d_in[13];
  const float* vwu      = (const float*)d_in[14];
  const float* vwd      = (const float*)d_in[15];
  const float* swg      = (const float*)d_in[16];
  const float* swu      = (const float*)d_in[17];
  const float* swd      = (const float*)d_in[18];
  float* out = (float*)d_out;

  char* ws = (char*)d_ws;
  size_t off = 0;
  auto alloc = [&](size_t bytes) -> void* {
    void* p = ws + off;
    off += (bytes + 255) & ~(size_t)255;
    return p;
  };
  u16*   xbh   = (u16*)alloc((size_t)TT * HID * 2);
  u16*   xbl   = (u16*)alloc((size_t)TT * HID * 2);
  float* qkv   = (float*)alloc((size_t)TT * QKVN * 4);
  u16*   aoH   = (u16*)alloc((size_t)TT * HID * 2);
  u16*   aoL   = (u16*)alloc((size_t)TT * HID * 2);
  float* hbuf  = (float*)alloc((size_t)TT * HID * 4);
  float* x2    = (float*)alloc((size_t)TT * HID * 4);
  u16*   xb2   = (u16*)alloc((size_t)TT * HID * 2);
  float* moe   = (float*)alloc((size_t)TT * HID * 4);
  u16*   ACT   = (u16*)alloc((SBASE + (size_t)TT * 1024) * 2);
  u16*   wqkvPH= (u16*)alloc((size_t)HID * QKVN * 2);
  u16*   wqkvPL= (u16*)alloc((size_t)HID * QKVN * 2);
  u16*   woPH  = (u16*)alloc((size_t)HID * HID * 2);
  u16*   woPL  = (u16*)alloc((size_t)HID * HID * 2);
  int*   counts= (int*)alloc(128 * 4);
  int*   rowoff= (int*)alloc(129 * 4);
  int*   ptok  = (int*)alloc((size_t)128 * TT * 4);
  float* pwgt  = (float*)alloc((size_t)128 * TT * 4);

  hipMemsetAsync(counts, 0, 128 * 4, stream);
  hipMemsetAsync(moe, 0, (size_t)TT * HID * 4, stream);

  // one-time weight packing (hi/lo bf16, k-packed-8)
  convert_w<<<dim3(QKVN / 256, 128), 256, 0, stream>>>(w_qkv, QKVN, wqkvPH, wqkvPL);
  convert_w<<<dim3(HID / 256, 128), 256, 0, stream>>>(w_o, HID, woPH, woPL);

  // pre-gate path, split-bf16 precision
  rmsnorm_kernel<false, true, true><<<TT, 256, 0, stream>>>(hidden, ln1, nullptr, xbh, xbl);
  dense_split<false><<<dim3(QKVN / 32, 8), 256, 0, stream>>>(xbh, xbl, wqkvPH, wqkvPL, nullptr, qkv, QKVN);
  rope_kernel<<<TT, 256, 0, stream>>>(qkv, positions);
  attn_mfma<<<dim3(TT / 32, NHEAD), 128, 0, stream>>>(qkv, aoH, aoL);
  dense_split<true><<<dim3(HID / 32, 8), 256, 0, stream>>>(aoH, aoL, woPH, woPL, hidden, hbuf, HID);
  rmsnorm_kernel<true, true, false><<<TT, 256, 0, stream>>>(hbuf, ln2, x2, xb2, nullptr);
  gate_kernel<<<TT, 256, 0, stream>>>(x2, vmask, tgw, vgw, cbias, counts, ptok, pwgt);
  scan_kernel<<<1, 64, 0, stream>>>(counts, rowoff);

  // MoE + shared MLP (bf16 slab MFMA, round-3 proven)
  gateup_mfma<I_S, 2><<<dim3(I_S / 32, 8), 256, 0, stream>>>(xb2, swg, swu, nullptr, nullptr, nullptr, rowoff, ACT);
  gateup_mfma<I_T, 0><<<dim3(I_T / 32, NEXP), 256, 0, stream>>>(xb2, twg, twu, counts, ptok, pwgt, rowoff, ACT);
  gateup_mfma<I_V, 1><<<dim3(I_V / 32, NEXP), 256, 0, stream>>>(xb2, vwg, vwu, counts, ptok, pwgt, rowoff, ACT);

  down_mfma<I_S, 2><<<dim3(HID / 64, 8), 256, 0, stream>>>(ACT, swd, nullptr, nullptr, rowoff, moe);
  down_mfma<I_T, 0><<<dim3(HID / 64, NEXP), 256, 0, stream>>>(ACT, twd, counts, ptok, rowoff, moe);
  down_mfma<I_V, 1><<<dim3(HID / 64, NEXP), 256, 0, stream>>>(ACT, vwd, counts, ptok, rowoff, moe);

  add2_kernel<<<(TT * HID) / 1024, 256, 0, stream>>>(hbuf, moe, out);
}

// Round 5
// 970.984 us; speedup vs baseline: 3.7419x; 1.4372x over previous
//
#include <hip/hip_runtime.h>
#include <hip/hip_bf16.h>
#include <math.h>

#define TT   2048
#define HID  1024
#define NHEAD 8
#define NKVH  2
#define HD   128
#define QKVN 1536
#define NEXP 64
#define NTOP 6
#define I_T  512
#define I_V  256
#define I_S  1024
#define SBASE ((size_t)12288 * 512)   // ACT elem offset of shared region

typedef unsigned short u16;
typedef __attribute__((ext_vector_type(8))) short short8v;
typedef __attribute__((ext_vector_type(4))) float f32x4;

__device__ inline u16 f2bf(float f) {
  __hip_bfloat16 h = __float2bfloat16(f);
  return *reinterpret_cast<u16*>(&h);
}
__device__ inline float bfu2f(u16 u) {
  unsigned x = ((unsigned)u) << 16;
  return __uint_as_float(x);
}
__device__ inline void split2(float f, u16& h, u16& l) {
  h = f2bf(f);
  l = f2bf(f - bfu2f(h));
}
__device__ inline void split8(const float* f, u16* h, u16* l) {
#pragma unroll
  for (int i = 0; i < 8; ++i) split2(f[i], h[i], l[i]);
}

__device__ inline f32x4 mfma16(short8v a, short8v b, f32x4 c) {
  return __builtin_amdgcn_mfma_f32_16x16x32_bf16(a, b, c, 0, 0, 0);
}

// ---- streaming weight-chunk staging: 128 k-rows x 32 cols, fp32 -> bf16 LDS
// LDS layout (k-packed-8): elem(k,c) at ((k>>3)*32 + c)*8 + (k&7)
__device__ inline void wload(const float* __restrict__ W, int ldw, int c0, int kc,
                             float4* r) {
  const int t = threadIdx.x;
  const int c4 = (t & 7) << 2;
  const int r0 = t >> 3;
#pragma unroll
  for (int j = 0; j < 4; ++j)
    r[j] = *(const float4*)&W[(size_t)(kc + r0 + j * 32) * ldw + c0 + c4];
}
__device__ inline void wwrite(const float4* r, u16* lds) {
  const int t = threadIdx.x;
  const int c4 = (t & 7) << 2;
  const int r0 = t >> 3;
#pragma unroll
  for (int j = 0; j < 4; ++j) {
    int k = r0 + j * 32;
    u16* dst = lds + ((k >> 3) * 32) * 8 + (k & 7);
    dst[(c4 + 0) * 8] = f2bf(r[j].x);
    dst[(c4 + 1) * 8] = f2bf(r[j].y);
    dst[(c4 + 2) * 8] = f2bf(r[j].z);
    dst[(c4 + 3) * 8] = f2bf(r[j].w);
  }
}

// ---------------- RMSNorm (templated outputs: fp32, bf16-hi, bf16-lo) ----------------
template<bool F32, bool BF, bool LO>
__global__ __launch_bounds__(256) void rmsnorm_kernel(const float* __restrict__ x,
                                                      const float* __restrict__ w,
                                                      float* __restrict__ o32,
                                                      u16* __restrict__ obfH,
                                                      u16* __restrict__ obfL) {
  const int row = blockIdx.x;
  const int t = threadIdx.x;
  const float4 v = *(const float4*)(x + (size_t)row * HID + t * 4);
  float ss = v.x*v.x + v.y*v.y + v.z*v.z + v.w*v.w;
#pragma unroll
  for (int m = 32; m >= 1; m >>= 1) ss += __shfl_xor(ss, m);
  __shared__ float red[4];
  __shared__ float rrs;
  if ((t & 63) == 0) red[t >> 6] = ss;
  __syncthreads();
  if (t == 0) rrs = rsqrtf((red[0] + red[1] + red[2] + red[3]) * (1.0f / HID) + 1e-5f);
  __syncthreads();
  const float rr = rrs;
  const float4 wv = *(const float4*)(w + t * 4);
  float o[4];
  o[0] = v.x * wv.x * rr; o[1] = v.y * wv.y * rr;
  o[2] = v.z * wv.z * rr; o[3] = v.w * wv.w * rr;
  if (F32) *(float4*)(o32 + (size_t)row * HID + t * 4) = *(float4*)o;
  if (BF) {
    u16 h[4], l[4];
#pragma unroll
    for (int i = 0; i < 4; ++i) split2(o[i], h[i], l[i]);
    *(uint2*)(obfH + (size_t)row * HID + t * 4) = *(uint2*)h;
    if (LO) *(uint2*)(obfL + (size_t)row * HID + t * 4) = *(uint2*)l;
  }
}

// ---------------- pack W fp32 [K=1024][N] -> hi/lo bf16, k-packed-8 slabs of 32 cols ---
__global__ __launch_bounds__(256) void convert_w(const float* __restrict__ W, int N,
                                                 u16* __restrict__ PH,
                                                 u16* __restrict__ PL) {
  const int c = blockIdx.x * 256 + threadIdx.x;
  const int k8 = blockIdx.y;
  float f[8];
#pragma unroll
  for (int e = 0; e < 8; ++e) f[e] = W[(size_t)(k8 * 8 + e) * N + c];
  u16 h8[8], l8[8];
  split8(f, h8, l8);
  size_t gi = ((size_t)(c >> 5) * 128 + k8) * 256 + (size_t)(c & 31) * 8;
  *(uint4*)&PH[gi] = *(uint4*)h8;
  *(uint4*)&PL[gi] = *(uint4*)l8;
}

// ---------------- dense split-bf16 GEMM (round-4, passing) ----------------
template<bool RES>
__global__ __launch_bounds__(256) void dense_split(const u16* __restrict__ AH,
                                                   const u16* __restrict__ AL,
                                                   const u16* __restrict__ WPH,
                                                   const u16* __restrict__ WPL,
                                                   const float* __restrict__ resid,
                                                   float* __restrict__ C, int N) {
  __shared__ u16 sWH[32768], sWL[32768];
  __shared__ u16 sAH[4096],  sAL[4096];
  const int t = threadIdx.x;
  const int cs = blockIdx.x;
  const int c0 = cs * 32;
  const int rows = TT / gridDim.y;
  const int mstart = blockIdx.y * rows, mend = mstart + rows;
  {
    const u16* gh = WPH + (size_t)cs * 32768;
    const u16* gl = WPL + (size_t)cs * 32768;
#pragma unroll
    for (int r = 0; r < 16; ++r) {
      int i8 = (t + 256 * r) * 8;
      *(uint4*)&sWH[i8] = *(const uint4*)&gh[i8];
      *(uint4*)&sWL[i8] = *(const uint4*)&gl[i8];
    }
  }
  const int w = t >> 6, lane = t & 63;
  const int rowHalf = (w & 1) << 4, colHalf = (w >> 1) << 4;
  for (int m0 = mstart; m0 < mend; m0 += 32) {
    f32x4 hh = {0.f,0.f,0.f,0.f}, hl = {0.f,0.f,0.f,0.f};
    f32x4 lh = {0.f,0.f,0.f,0.f}, ll = {0.f,0.f,0.f,0.f};
    for (int kc = 0; kc < HID; kc += 128) {
      __syncthreads();
#pragma unroll
      for (int r = 0; r < 2; ++r) {
        int task = t + 256 * r;
        int row = task >> 4, kg = task & 15;
        size_t g = (size_t)(m0 + row) * HID + kc + kg * 8;
        *(uint4*)&sAH[(kg * 32 + row) * 8] = *(const uint4*)&AH[g];
        *(uint4*)&sAL[(kg * 32 + row) * 8] = *(const uint4*)&AL[g];
      }
      __syncthreads();
#pragma unroll
      for (int ks = 0; ks < 4; ++ks) {
        int arow = rowHalf + (lane & 15);
        int akg = ks * 4 + (lane >> 4);
        short8v ah = *(const short8v*)&sAH[(akg * 32 + arow) * 8];
        short8v al = *(const short8v*)&sAL[(akg * 32 + arow) * 8];
        int wcol = colHalf + (lane & 15);
        int wkg = (kc >> 3) + ks * 4 + (lane >> 4);
        short8v bh = *(const short8v*)&sWH[(wkg * 32 + wcol) * 8];
        short8v bl = *(const short8v*)&sWL[(wkg * 32 + wcol) * 8];
        hh = mfma16(ah, bh, hh);
        hl = mfma16(ah, bl, hl);
        lh = mfma16(al, bh, lh);
        ll = mfma16(al, bl, ll);
      }
    }
    f32x4 acc = (hh + hl) + (lh + ll);
#pragma unroll
    for (int i = 0; i < 4; ++i) {
      int r = m0 + rowHalf + ((lane >> 4) << 2) + i;
      int c = c0 + colHalf + (lane & 15);
      float v = acc[i];
      if (RES) v += resid[(size_t)r * N + c];
      C[(size_t)r * N + c] = v;
    }
  }
}

// ---------------- mRoPE (in-place on q,k of qkv, fp32) ----------------
__global__ __launch_bounds__(256) void rope_kernel(float* __restrict__ qkv,
                                                   const int* __restrict__ pos) {
  const int tok = blockIdx.x;
  const int t = threadIdx.x;
  float* row = qkv + (size_t)tok * QKVN;
  for (int p = t; p < 640; p += 256) {
    int fi, base;
    if (p < 512) { int head = p >> 6; fi = p & 63; base = head * HD; }
    else         { int pp = p - 512; int head = pp >> 6; fi = pp & 63; base = NHEAD * HD + head * HD; }
    int axis = (fi < 22) ? 0 : (fi < 44 ? 1 : 2);
    float posv = (float)pos[axis * TT + tok];
    float invf = powf(500000.0f, -((float)(2 * fi)) / 128.0f);
    float ang = posv * invf;
    float s, c;
    sincosf(ang, &s, &c);
    float x1 = row[base + 2 * fi], x2 = row[base + 2 * fi + 1];
    row[base + 2 * fi]     = x1 * c - x2 * s;
    row[base + 2 * fi + 1] = x1 * s + x2 * c;
  }
}

// ---------------- split-bf16 MFMA flash attention (round-4, passing) ----------------
__global__ __launch_bounds__(128) void attn_mfma(const float* __restrict__ qkv,
                                                 u16* __restrict__ aoH,
                                                 u16* __restrict__ aoL) {
  const int qb = blockIdx.x;
  const int head = blockIdx.y;
  const int t = threadIdx.x;
  const int w = t >> 6, lane = t & 63;
  const int qw0 = qb * 32 + w * 16;
  const int kvh = head >> 2;
  const int kbase = NHEAD * HD + kvh * HD;
  const int vbase = (NHEAD + NKVH) * HD + kvh * HD;

  __shared__ u16 Kh[4096], Kl[4096];
  __shared__ u16 Vh[4096], Vl[4096];
  __shared__ u16 Ph[2][512], Pl[2][512];

  short8v qh[4], ql[4];
  {
    const int m = lane & 15, g = lane >> 4;
    const float* qp = qkv + (size_t)(qw0 + m) * QKVN + head * HD + g * 8;
#pragma unroll
    for (int dc = 0; dc < 4; ++dc) {
      float4 v0 = *(const float4*)(qp + dc * 32);
      float4 v1 = *(const float4*)(qp + dc * 32 + 4);
      float f[8] = {v0.x, v0.y, v0.z, v0.w, v1.x, v1.y, v1.z, v1.w};
      u16 h8[8], l8[8];
      split8(f, h8, l8);
      qh[dc] = *(short8v*)h8;
      ql[dc] = *(short8v*)l8;
    }
  }

  f32x4 o[8];
#pragma unroll
  for (int dt = 0; dt < 8; ++dt) o[dt] = (f32x4){0.f,0.f,0.f,0.f};
  float mr[4] = {-INFINITY, -INFINITY, -INFINITY, -INFINITY};
  float lr[4] = {0.f, 0.f, 0.f, 0.f};
  const float scale = 0.08838834764831845f;

  const int nkt = qb + 1;
  for (int kt = 0; kt < nkt; ++kt) {
    const int kv0 = kt * 32;
#pragma unroll
    for (int r = 0; r < 4; ++r) {
      int task = t + 128 * r;
      int key = task & 31, d8 = task >> 5;
      const float* kp = qkv + (size_t)(kv0 + key) * QKVN + kbase + d8 * 8;
      float4 a = *(const float4*)kp, b = *(const float4*)(kp + 4);
      float f[8] = {a.x, a.y, a.z, a.w, b.x, b.y, b.z, b.w};
      u16 h8[8], l8[8];
      split8(f, h8, l8);
      int base = (d8 * 32 + key) * 8;
      *(uint4*)&Kh[base] = *(uint4*)h8;
      *(uint4*)&Kl[base] = *(uint4*)l8;
    }
#pragma unroll
    for (int r = 0; r < 4; ++r) {
      int task = t + 128 * r;
      int c = task & 127, k8 = task >> 7;
      float f[8];
#pragma unroll
      for (int e = 0; e < 8; ++e)
        f[e] = qkv[(size_t)(kv0 + k8 * 8 + e) * QKVN + vbase + c];
      u16 h8[8], l8[8];
      split8(f, h8, l8);
      int base = (k8 * 128 + c) * 8;
      *(uint4*)&Vh[base] = *(uint4*)h8;
      *(uint4*)&Vl[base] = *(uint4*)l8;
    }
    __syncthreads();
    if (kv0 <= qw0 + 15) {
      f32x4 s[2];
#pragma unroll
      for (int nt = 0; nt < 2; ++nt) {
        f32x4 shh = {0.f,0.f,0.f,0.f}, shl = {0.f,0.f,0.f,0.f};
        f32x4 slh = {0.f,0.f,0.f,0.f}, sll = {0.f,0.f,0.f,0.f};
#pragma unroll
        for (int dc = 0; dc < 4; ++dc) {
          int kb_ = ((dc * 4 + (lane >> 4)) * 32 + nt * 16 + (lane & 15)) * 8;
          short8v bh = *(const short8v*)&Kh[kb_];
          short8v bl = *(const short8v*)&Kl[kb_];
          shh = mfma16(qh[dc], bh, shh);
          shl = mfma16(qh[dc], bl, shl);
          slh = mfma16(ql[dc], bh, slh);
          sll = mfma16(ql[dc], bl, sll);
        }
        s[nt] = (shh + shl) + (slh + sll);
      }
      float rmax[4];
#pragma unroll
      for (int i = 0; i < 4; ++i) {
        int qrow = qw0 + ((lane >> 4) << 2) + i;
#pragma unroll
        for (int nt = 0; nt < 2; ++nt) {
          int key = kv0 + nt * 16 + (lane & 15);
          float v = s[nt][i] * scale;
          s[nt][i] = (key <= qrow) ? v : -INFINITY;
        }
        rmax[i] = fmaxf(s[0][i], s[1][i]);
      }
#pragma unroll
      for (int msk = 1; msk <= 8; msk <<= 1)
#pragma unroll
        for (int i = 0; i < 4; ++i) rmax[i] = fmaxf(rmax[i], __shfl_xor(rmax[i], msk));
      float corr[4];
#pragma unroll
      for (int i = 0; i < 4; ++i) {
        float mn = fmaxf(mr[i], rmax[i]);
        corr[i] = expf(mr[i] - mn);
        mr[i] = mn;
      }
      float p[2][4], ps[4];
#pragma unroll
      for (int nt = 0; nt < 2; ++nt)
#pragma unroll
        for (int i = 0; i < 4; ++i) p[nt][i] = expf(s[nt][i] - mr[i]);
#pragma unroll
      for (int i = 0; i < 4; ++i) ps[i] = p[0][i] + p[1][i];
#pragma unroll
      for (int msk = 1; msk <= 8; msk <<= 1)
#pragma unroll
        for (int i = 0; i < 4; ++i) ps[i] += __shfl_xor(ps[i], msk);
#pragma unroll
      for (int i = 0; i < 4; ++i) lr[i] = lr[i] * corr[i] + ps[i];
#pragma unroll
      for (int dt = 0; dt < 8; ++dt)
#pragma unroll
        for (int i = 0; i < 4; ++i) o[dt][i] *= corr[i];
      u16* phw = Ph[w];
      u16* plw = Pl[w];
#pragma unroll
      for (int nt = 0; nt < 2; ++nt)
#pragma unroll
        for (int i = 0; i < 4; ++i) {
          int q = ((lane >> 4) << 2) + i;
          int kk = nt * 16 + (lane & 15);
          int idx = ((kk >> 3) * 16 + q) * 8 + (kk & 7);
          u16 h, l;
          split2(p[nt][i], h, l);
          phw[idx] = h;
          plw[idx] = l;
        }
      asm volatile("s_waitcnt lgkmcnt(0)" ::: "memory");
      __builtin_amdgcn_sched_barrier(0);
      {
        int pbase = ((lane >> 4) * 16 + (lane & 15)) * 8;
        short8v pah = *(const short8v*)&phw[pbase];
        short8v pal = *(const short8v*)&plw[pbase];
#pragma unroll
        for (int dt = 0; dt < 8; ++dt) {
          int vb_ = ((lane >> 4) * 128 + dt * 16 + (lane & 15)) * 8;
          short8v vh = *(const short8v*)&Vh[vb_];
          short8v vl = *(const short8v*)&Vl[vb_];
          o[dt] = mfma16(pah, vh, o[dt]);
          o[dt] = mfma16(pah, vl, o[dt]);
          o[dt] = mfma16(pal, vh, o[dt]);
        }
      }
    }
    __syncthreads();
  }
  float inv[4];
#pragma unroll
  for (int i = 0; i < 4; ++i) inv[i] = 1.f / lr[i];
#pragma unroll
  for (int dt = 0; dt < 8; ++dt)
#pragma unroll
    for (int i = 0; i < 4; ++i) {
      int qrow = qw0 + ((lane >> 4) << 2) + i;
      int col = head * HD + dt * 16 + (lane & 15);
      u16 h, l;
      split2(o[dt][i] * inv[i], h, l);
      aoH[(size_t)qrow * HID + col] = h;
      aoL[(size_t)qrow * HID + col] = l;
    }
}

// ---------------- Gating (fp32, known-good) ----------------
__global__ __launch_bounds__(256) void gate_kernel(const float* __restrict__ x2,
                                                   const int* __restrict__ vmask,
                                                   const float* __restrict__ tg,
                                                   const float* __restrict__ vg,
                                                   const float* __restrict__ cbias,
                                                   int* __restrict__ counts,
                                                   int* __restrict__ ptok,
                                                   float* __restrict__ pw) {
  const int tok = blockIdx.x;
  const int t = threadIdx.x;
  __shared__ float xs[HID];
  __shared__ float sc[NEXP];
  __shared__ float sb[NEXP];
  *(float4*)&xs[t * 4] = *(const float4*)(x2 + (size_t)tok * HID + t * 4);
  __syncthreads();
  const int vis = (vmask[tok] != 0) ? 1 : 0;
  const float* gw = vis ? vg : tg;
  if (t < NEXP) {
    float acc = 0.f;
    for (int h = 0; h < HID; ++h) acc += xs[h] * gw[h * NEXP + t];
    float s = 1.f / (1.f + expf(-acc));
    sc[t] = s;
    sb[t] = s + cbias[vis * NEXP + t];
  }
  __syncthreads();
  if (t == 0) {
    int chosen[NTOP];
    unsigned long long usedm = 0ULL;
    float wsum = 0.f;
    for (int k = 0; k < NTOP; ++k) {
      float best = -1e30f; int bi = 0;
      for (int e = 0; e < NEXP; ++e) {
        if ((usedm >> e) & 1ULL) continue;
        if (sb[e] > best) { best = sb[e]; bi = e; }
      }
      usedm |= (1ULL << bi);
      chosen[k] = bi;
      wsum += sc[bi];
    }
    const float inv = 1.f / wsum;
    for (int k = 0; k < NTOP; ++k) {
      int e = chosen[k];
      int slot = vis * NEXP + e;
      int pos = atomicAdd(&counts[slot], 1);
      ptok[slot * TT + pos] = tok;
      pw[slot * TT + pos] = sc[e] * inv;
    }
  }
}

__global__ void scan_kernel(const int* __restrict__ counts, int* __restrict__ rowoff) {
  if (threadIdx.x == 0 && blockIdx.x == 0) {
    int s = 0;
    for (int i = 0; i < 128; ++i) { rowoff[i] = s; s += counts[i]; }
    rowoff[128] = s;
  }
}

template<int MODE>
__device__ inline void act_base(const int* rowoff, int slot, size_t& eb, int& stride) {
  if (MODE == 0) { eb = (size_t)rowoff[slot] * 512; stride = 512; }
  else if (MODE == 1) {
    int Rt = rowoff[64];
    eb = (size_t)Rt * 512 + (size_t)(rowoff[slot] - Rt) * 256; stride = 256;
  } else { eb = SBASE; stride = 1024; }
}

// ---------------- streaming gate+up: weights K-chunk double-buffered, tokens resident ---
// grid: MODE 0/1: (IDIM/32, 64); MODE 2: (IDIM/32, 8 token groups of 256)
template<int IDIM, int MODE>
__global__ __launch_bounds__(256) void gateup_stream(const u16* __restrict__ X,
                                                     const float* __restrict__ WG,
                                                     const float* __restrict__ WU,
                                                     const int* __restrict__ counts,
                                                     const int* __restrict__ ptok,
                                                     const float* __restrict__ pw,
                                                     const int* __restrict__ rowoff,
                                                     u16* __restrict__ ACT) {
  __shared__ u16 sG[2][4096], sU[2][4096];
  __shared__ int toksL[256];
  __shared__ float twsL[256];
  const int c0 = blockIdx.x * 32;
  int cnt, mstart, mend, slot = 0;
  size_t eb; int stride;
  const float *wgp, *wup;
  if (MODE == 2) {
    cnt = TT; mstart = blockIdx.y * 256; mend = mstart + 256;
    eb = SBASE; stride = 1024;
    wgp = WG; wup = WU;
  } else {
    const int e = blockIdx.y;
    slot = (MODE == 1 ? NEXP : 0) + e;
    cnt = counts[slot];
    mstart = 0; mend = cnt;
    act_base<MODE>(rowoff, slot, eb, stride);
    wgp = WG + (size_t)e * HID * IDIM;
    wup = WU + (size_t)e * HID * IDIM;
  }
  if (mstart >= mend) return;
  const int w = threadIdx.x >> 6, lane = threadIdx.x & 63;
  const int lrow = lane & 15, loct = lane >> 4;

  for (int m0 = mstart; m0 < mend; m0 += 256) {
    {
      int gi = m0 + threadIdx.x;
      int tok = 0; float tw = 0.f;
      if (gi < cnt) {
        tok = (MODE == 2) ? gi : ptok[slot * TT + gi];
        tw  = (MODE == 2) ? 1.f : pw[slot * TT + gi];
      }
      toksL[threadIdx.x] = tok; twsL[threadIdx.x] = tw;
    }
    float4 rg[4], ru[4];
    wload(wgp, IDIM, c0, 0, rg);
    wload(wup, IDIM, c0, 0, ru);
    __syncthreads();                       // toks staged (and prev pass done)
    wwrite(rg, sG[0]);
    wwrite(ru, sU[0]);
    const u16* xr[4];
#pragma unroll
    for (int tt = 0; tt < 4; ++tt)
      xr[tt] = X + (size_t)toksL[(w + tt * 4) * 16 + lrow] * HID;
    f32x4 aG[4][2], aU[4][2];
#pragma unroll
    for (int tt = 0; tt < 4; ++tt)
#pragma unroll
      for (int fr = 0; fr < 2; ++fr) {
        aG[tt][fr] = (f32x4){0.f,0.f,0.f,0.f};
        aU[tt][fr] = (f32x4){0.f,0.f,0.f,0.f};
      }
    __syncthreads();                       // buf0 ready
    for (int c = 0; c < HID / 128; ++c) {
      const int cur = c & 1;
      if (c + 1 < HID / 128) {
        wload(wgp, IDIM, c0, (c + 1) * 128, rg);   // issue early (T14)
        wload(wup, IDIM, c0, (c + 1) * 128, ru);
      }
#pragma unroll
      for (int ks = 0; ks < 4; ++ks) {
        const int boff = ((ks * 4 + loct) * 32 + lrow) * 8;
        short8v bg0 = *(const short8v*)&sG[cur][boff];
        short8v bg1 = *(const short8v*)&sG[cur][boff + 128];
        short8v bu0 = *(const short8v*)&sU[cur][boff];
        short8v bu1 = *(const short8v*)&sU[cur][boff + 128];
#pragma unroll
        for (int tt = 0; tt < 4; ++tt) {
          short8v a = *(const short8v*)&xr[tt][c * 128 + ks * 32 + loct * 8];
          aG[tt][0] = mfma16(a, bg0, aG[tt][0]);
          aG[tt][1] = mfma16(a, bg1, aG[tt][1]);
          aU[tt][0] = mfma16(a, bu0, aU[tt][0]);
          aU[tt][1] = mfma16(a, bu1, aU[tt][1]);
        }
      }
      if (c + 1 < HID / 128) {
        wwrite(rg, sG[cur ^ 1]);           // write late (after MFMA)
        wwrite(ru, sU[cur ^ 1]);
      }
      __syncthreads();
    }
#pragma unroll
    for (int tt = 0; tt < 4; ++tt) {
      const int ti = w + tt * 4;
#pragma unroll
      for (int i = 0; i < 4; ++i) {
        const int r = loct * 4 + i;
        const int gi = m0 + ti * 16 + r;
        if (gi < cnt) {
          const float twv = twsL[ti * 16 + r];
#pragma unroll
          for (int fr = 0; fr < 2; ++fr) {
            float g = aG[tt][fr][i], u = aU[tt][fr][i];
            float a = g / (1.f + expf(-g)) * u * twv;
            ACT[eb + (size_t)gi * stride + c0 + fr * 16 + lrow] = f2bf(a);
          }
        }
      }
    }
    __syncthreads();                       // protect toksL before next pass
  }
}

// ---------------- streaming down-proj: atomicAdd into OUT ----------------
// grid: MODE 0/1: (HID/32, 64); MODE 2: (HID/32, 8)
template<int KDIM, int MODE>
__global__ __launch_bounds__(256) void down_stream(const u16* __restrict__ ACT,
                                                   const float* __restrict__ WD,
                                                   const int* __restrict__ counts,
                                                   const int* __restrict__ ptok,
                                                   const int* __restrict__ rowoff,
                                                   float* __restrict__ OUT) {
  __shared__ u16 sW[2][4096];
  __shared__ int toksL[256];
  const int c0 = blockIdx.x * 32;
  int cnt, mstart, mend, slot = 0;
  size_t eb; int stride;
  const float* wdp;
  if (MODE == 2) {
    cnt = TT; mstart = blockIdx.y * 256; mend = mstart + 256;
    eb = SBASE; stride = 1024;
    wdp = WD;
  } else {
    const int e = blockIdx.y;
    slot = (MODE == 1 ? NEXP : 0) + e;
    cnt = counts[slot];
    mstart = 0; mend = cnt;
    act_base<MODE>(rowoff, slot, eb, stride);
    wdp = WD + (size_t)e * KDIM * HID;
  }
  if (mstart >= mend) return;
  const int w = threadIdx.x >> 6, lane = threadIdx.x & 63;
  const int lrow = lane & 15, loct = lane >> 4;
  constexpr int NC = KDIM / 128;

  for (int m0 = mstart; m0 < mend; m0 += 256) {
    {
      int gi = m0 + threadIdx.x;
      int tok = 0;
      if (gi < cnt) tok = (MODE == 2) ? gi : ptok[slot * TT + gi];
      toksL[threadIdx.x] = tok;
    }
    float4 rw[4];
    wload(wdp, HID, c0, 0, rw);
    __syncthreads();
    wwrite(rw, sW[0]);
    const u16* ar[4];
#pragma unroll
    for (int tt = 0; tt < 4; ++tt) {
      int gi = m0 + (w + tt * 4) * 16 + lrow;
      int gc = (gi < cnt) ? gi : (cnt - 1);
      ar[tt] = ACT + eb + (size_t)gc * stride;
    }
    f32x4 acc[4][2];
#pragma unroll
    for (int tt = 0; tt < 4; ++tt)
#pragma unroll
      for (int fr = 0; fr < 2; ++fr) acc[tt][fr] = (f32x4){0.f,0.f,0.f,0.f};
    __syncthreads();
    for (int c = 0; c < NC; ++c) {
      const int cur = c & 1;
      if (c + 1 < NC) wload(wdp, HID, c0, (c + 1) * 128, rw);
#pragma unroll
      for (int ks = 0; ks < 4; ++ks) {
        const int boff = ((ks * 4 + loct) * 32 + lrow) * 8;
        short8v b0 = *(const short8v*)&sW[cur][boff];
        short8v b1 = *(const short8v*)&sW[cur][boff + 128];
#pragma unroll
        for (int tt = 0; tt < 4; ++tt) {
          short8v a = *(const short8v*)&ar[tt][c * 128 + ks * 32 + loct * 8];
          acc[tt][0] = mfma16(a, b0, acc[tt][0]);
          acc[tt][1] = mfma16(a, b1, acc[tt][1]);
        }
      }
      if (c + 1 < NC) wwrite(rw, sW[cur ^ 1]);
      __syncthreads();
    }
#pragma unroll
    for (int tt = 0; tt < 4; ++tt) {
      const int ti = w + tt * 4;
#pragma unroll
      for (int i = 0; i < 4; ++i) {
        const int r = loct * 4 + i;
        const int gi = m0 + ti * 16 + r;
        if (gi < cnt) {
          const int tok = toksL[ti * 16 + r];
#pragma unroll
          for (int fr = 0; fr < 2; ++fr)
            atomicAdd(&OUT[(size_t)tok * HID + c0 + fr * 16 + lrow], acc[tt][fr][i]);
        }
      }
    }
    __syncthreads();
  }
}

// ---------------- out = a + b ----------------
__global__ __launch_bounds__(256) void add2_kernel(const float* __restrict__ a,
                                                   const float* __restrict__ b,
                                                   float* __restrict__ out) {
  const size_t i = ((size_t)blockIdx.x * 256 + threadIdx.x) * 4;
  const float4 va = *(const float4*)(a + i);
  const float4 vb = *(const float4*)(b + i);
  float4 o;
  o.x = va.x + vb.x; o.y = va.y + vb.y; o.z = va.z + vb.z; o.w = va.w + vb.w;
  *(float4*)(out + i) = o;
}

extern "C" void kernel_launch(void* const* d_in, const int* in_sizes, int n_in,
                              void* d_out, int out_size, void* d_ws, size_t ws_size,
                              hipStream_t stream) {
  const float* hidden   = (const float*)d_in[0];
  const int*   positions= (const int*)d_in[1];
  const int*   vmask    = (const int*)d_in[2];
  const float* w_qkv    = (const float*)d_in[3];
  const float* w_o      = (const float*)d_in[4];
  const float* ln1      = (const float*)d_in[5];
  const float* ln2      = (const float*)d_in[6];
  const float* tgw      = (const float*)d_in[7];
  const float* vgw      = (const float*)d_in[8];
  const float* cbias    = (const float*)d_in[9];
  const float* twg      = (const float*)d_in[10];
  const float* twu      = (const float*)d_in[11];
  const float* twd      = (const float*)d_in[12];
  const float* vwg      = (const float*)d_in[13];
  const float* vwu      = (const float*)d_in[14];
  const float* vwd      = (const float*)d_in[15];
  const float* swg      = (const float*)d_in[16];
  const float* swu      = (const float*)d_in[17];
  const float* swd      = (const float*)d_in[18];
  float* out = (float*)d_out;

  char* ws = (char*)d_ws;
  size_t off = 0;
  auto alloc = [&](size_t bytes) -> void* {
    void* p = ws + off;
    off += (bytes + 255) & ~(size_t)255;
    return p;
  };
  u16*   xbh   = (u16*)alloc((size_t)TT * HID * 2);
  u16*   xbl   = (u16*)alloc((size_t)TT * HID * 2);
  float* qkv   = (float*)alloc((size_t)TT * QKVN * 4);
  u16*   aoH   = (u16*)alloc((size_t)TT * HID * 2);
  u16*   aoL   = (u16*)alloc((size_t)TT * HID * 2);
  float* hbuf  = (float*)alloc((size_t)TT * HID * 4);
  float* x2    = (float*)alloc((size_t)TT * HID * 4);
  u16*   xb2   = (u16*)alloc((size_t)TT * HID * 2);
  float* moe   = (float*)alloc((size_t)TT * HID * 4);
  u16*   ACT   = (u16*)alloc((SBASE + (size_t)TT * 1024) * 2);
  u16*   wqkvPH= (u16*)alloc((size_t)HID * QKVN * 2);
  u16*   wqkvPL= (u16*)alloc((size_t)HID * QKVN * 2);
  u16*   woPH  = (u16*)alloc((size_t)HID * HID * 2);
  u16*   woPL  = (u16*)alloc((size_t)HID * HID * 2);
  int*   counts= (int*)alloc(128 * 4);
  int*   rowoff= (int*)alloc(129 * 4);
  int*   ptok  = (int*)alloc((size_t)128 * TT * 4);
  float* pwgt  = (float*)alloc((size_t)128 * TT * 4);

  hipMemsetAsync(counts, 0, 128 * 4, stream);
  hipMemsetAsync(moe, 0, (size_t)TT * HID * 4, stream);

  // one-time weight packing (hi/lo bf16, k-packed-8) for dense GEMMs
  convert_w<<<dim3(QKVN / 256, 128), 256, 0, stream>>>(w_qkv, QKVN, wqkvPH, wqkvPL);
  convert_w<<<dim3(HID / 256, 128), 256, 0, stream>>>(w_o, HID, woPH, woPL);

  // pre-gate path, split-bf16 precision
  rmsnorm_kernel<false, true, true><<<TT, 256, 0, stream>>>(hidden, ln1, nullptr, xbh, xbl);
  dense_split<false><<<dim3(QKVN / 32, 8), 256, 0, stream>>>(xbh, xbl, wqkvPH, wqkvPL, nullptr, qkv, QKVN);
  rope_kernel<<<TT, 256, 0, stream>>>(qkv, positions);
  attn_mfma<<<dim3(TT / 32, NHEAD), 128, 0, stream>>>(qkv, aoH, aoL);
  dense_split<true><<<dim3(HID / 32, 8), 256, 0, stream>>>(aoH, aoL, woPH, woPL, hidden, hbuf, HID);
  rmsnorm_kernel<true, true, false><<<TT, 256, 0, stream>>>(hbuf, ln2, x2, xb2, nullptr);
  gate_kernel<<<TT, 256, 0, stream>>>(x2, vmask, tgw, vgw, cbias, counts, ptok, pwgt);
  scan_kernel<<<1, 64, 0, stream>>>(counts, rowoff);

  // MoE + shared MLP: streaming weight kernels
  gateup_stream<I_S, 2><<<dim3(I_S / 32, 8), 256, 0, stream>>>(xb2, swg, swu, nullptr, nullptr, nullptr, rowoff, ACT);
  gateup_stream<I_T, 0><<<dim3(I_T / 32, NEXP), 256, 0, stream>>>(xb2, twg, twu, counts, ptok, pwgt, rowoff, ACT);
  gateup_stream<I_V, 1><<<dim3(I_V / 32, NEXP), 256, 0, stream>>>(xb2, vwg, vwu, counts, ptok, pwgt, rowoff, ACT);

  down_stream<I_S, 2><<<dim3(HID / 32, 8), 256, 0, stream>>>(ACT, swd, nullptr, nullptr, rowoff, moe);
  down_stream<I_T, 0><<<dim3(HID / 32, NEXP), 256, 0, stream>>>(ACT, twd, counts, ptok, rowoff, moe);
  down_stream<I_V, 1><<<dim3(HID / 32, NEXP), 256, 0, stream>>>(ACT, vwd, counts, ptok, rowoff, moe);

  add2_kernel<<<(TT * HID) / 1024, 256, 0, stream>>>(hbuf, moe, out);
}